// Round 8
// baseline (264.338 us; speedup 1.0000x reference)
//
#include <hip/hip_runtime.h>
#include <float.h>

// ---------------------------------------------------------------------------
// VQ layer forward, MI355X. B=4, L=2048 (8192 tokens), D=1024, VQ_DIM=64,
// K_CODES=8192, EMA_K=5.
// Round 8: ONE distance GEMM pass. k_dist streams codes once; the MFMA acc
// tile feeds BOTH per-token argmin (registers, u-basis) and per-code top-5
// partials (per 128-token tile). Streamed E staged through one 16KB LDS
// buffer (reg-staged, issued one chunk ahead). Single MFMA chain (16 AGPR),
// 512-thread blocks, launch_bounds(512,4) -> 2 blocks/CU. Round-7 lesson:
// 4 chains + reg ping-pong = 128 VGPR = occupancy collapse.
// ---------------------------------------------------------------------------

typedef __attribute__((ext_vector_type(8)))  short bf16x8;   // 8 bf16 = 4 VGPR
typedef __attribute__((ext_vector_type(16))) float f32x16;   // MFMA 32x32 acc

__device__ __forceinline__ unsigned short f2bf(float x) {
  unsigned u = __float_as_uint(x);
  unsigned r = (u + 0x7fffu + ((u >> 16) & 1u)) >> 16;   // RNE
  return (unsigned short)r;
}
__device__ __forceinline__ float bf2f(unsigned short b) {
  return __uint_as_float(((unsigned)b) << 16);
}
// fragment-major layout: entity-block(32) x ks(4) x lh(2) x lane(32) x 8 elems
__device__ __forceinline__ size_t frag_off(int e, int ks, int lh) {
  return ((size_t)((((e >> 5) * 4 + ks) * 2 + lh) * 32 + (e & 31))) * 8;
}

// sorted-5 insert, plain strict < (requires ascending-index insertion order)
__device__ __forceinline__ void tins5(float& d0, float& d1, float& d2,
                                      float& d3, float& d4, int& i0, int& i1,
                                      int& i2, int& i3, int& i4, float dv,
                                      int iv) {
  if (dv < d4) {
    d4 = dv; i4 = iv;
    if (d4 < d3) { float t = d3; d3 = d4; d4 = t; int u = i3; i3 = i4; i4 = u; }
    if (d3 < d2) { float t = d2; d2 = d3; d3 = t; int u = i2; i2 = i3; i3 = u; }
    if (d2 < d1) { float t = d1; d1 = d2; d2 = t; int u = i1; i1 = i2; i2 = u; }
    if (d1 < d0) { float t = d0; d0 = d1; d1 = t; int u = i0; i0 = i1; i1 = u; }
  }
}
// sorted-5 insert, lexicographic (d, idx) — order-independent merges
__device__ __forceinline__ void lins5(float& d0, float& d1, float& d2,
                                      float& d3, float& d4, int& i0, int& i1,
                                      int& i2, int& i3, int& i4, float dv,
                                      int iv) {
  if (dv < d4 || (dv == d4 && iv < i4)) {
    d4 = dv; i4 = iv;
    if (d4 < d3 || (d4 == d3 && i4 < i3)) { float t = d3; d3 = d4; d4 = t; int u = i3; i3 = i4; i4 = u; }
    if (d3 < d2 || (d3 == d2 && i3 < i2)) { float t = d2; d2 = d3; d3 = t; int u = i2; i2 = i3; i3 = u; }
    if (d2 < d1 || (d2 == d1 && i2 < i1)) { float t = d1; d1 = d2; d2 = t; int u = i1; i1 = i2; i2 = u; }
    if (d1 < d0 || (d1 == d0 && i1 < i0)) { float t = d0; d0 = d1; d1 = t; int u = i0; i0 = i1; i1 = u; }
  }
}

// ---------------- Kernel 1: hp = normalize(h @ proj_w + b), + bf16 split ---
__global__ __launch_bounds__(256) void k_proj(
    const float* __restrict__ h, const float* __restrict__ w,
    const float* __restrict__ bias, float* __restrict__ hp_norm,
    float* __restrict__ h2, unsigned short* __restrict__ hpH,
    unsigned short* __restrict__ hpL) {
  __shared__ __align__(16) float hs[16 * 68];   // 16 tok x 64 k (pad 68)
  __shared__ __align__(16) float ws[64 * 64];   // 64 k x 64 dim
  const int tid = threadIdx.x;
  const int tb = blockIdx.x * 16;
  const int tok = tid >> 4;
  const int dimg = tid & 15;
  const float4* h4 = (const float4*)h;
  const float4* w4 = (const float4*)w;
  float4* ws4 = (float4*)ws;
  float4 acc = {0.f, 0.f, 0.f, 0.f};
  for (int ch = 0; ch < 16; ++ch) {
    __syncthreads();
    *(float4*)&hs[tok * 68 + dimg * 4] = h4[(size_t)(tb + tok) * 256 + ch * 16 + dimg];
#pragma unroll
    for (int i = 0; i < 4; ++i) {
      int idx = tid + i * 256;
      int k = idx >> 4, dq = idx & 15;
      ws4[k * 16 + dq] = w4[(size_t)(ch * 64 + k) * 16 + dq];
    }
    __syncthreads();
#pragma unroll 8
    for (int k = 0; k < 64; ++k) {
      float hv = hs[tok * 68 + k];
      float4 wv = *(const float4*)&ws[k * 64 + dimg * 4];
      acc.x = fmaf(hv, wv.x, acc.x);
      acc.y = fmaf(hv, wv.y, acc.y);
      acc.z = fmaf(hv, wv.z, acc.z);
      acc.w = fmaf(hv, wv.w, acc.w);
    }
  }
  const float4 bv = ((const float4*)bias)[dimg];
  acc.x += bv.x; acc.y += bv.y; acc.z += bv.z; acc.w += bv.w;
  float sq = acc.x * acc.x + acc.y * acc.y + acc.z * acc.z + acc.w * acc.w;
#pragma unroll
  for (int o = 1; o <= 8; o <<= 1) sq += __shfl_xor(sq, o, 64);
  float nrm = sqrtf(sq);
  float4 vn;
  vn.x = acc.x / nrm; vn.y = acc.y / nrm; vn.z = acc.z / nrm; vn.w = acc.w / nrm;
  ((float4*)hp_norm)[(size_t)(tb + tok) * 16 + dimg] = vn;
  unsigned short hx = f2bf(vn.x), hy = f2bf(vn.y), hz = f2bf(vn.z), hw = f2bf(vn.w);
  uint2 hi_pack, lo_pack;
  hi_pack.x = (unsigned)hx | ((unsigned)hy << 16);
  hi_pack.y = (unsigned)hz | ((unsigned)hw << 16);
  lo_pack.x = (unsigned)f2bf(vn.x - bf2f(hx)) | ((unsigned)f2bf(vn.y - bf2f(hy)) << 16);
  lo_pack.y = (unsigned)f2bf(vn.z - bf2f(hz)) | ((unsigned)f2bf(vn.w - bf2f(hw)) << 16);
  {
    int ks = dimg >> 2, lh = (dimg >> 1) & 1, half = dimg & 1;
    size_t off = frag_off(tb + tok, ks, lh) + half * 4;
    *(uint2*)(hpH + off) = hi_pack;
    *(uint2*)(hpL + off) = lo_pack;
  }
  float s2 = vn.x * vn.x + vn.y * vn.y + vn.z * vn.z + vn.w * vn.w;
#pragma unroll
  for (int o = 1; o <= 8; o <<= 1) s2 += __shfl_xor(s2, o, 64);
  if (dimg == 0) h2[tb + tok] = s2;
}

// ---------------- Kernel 2: E-normalize + initcount + wT transpose ---------
// grid 2096: [0,2048) enorm, [2048,2080) newcount=count, [2080,2096) wT.
__global__ __launch_bounds__(256) void k_enorm(
    const float* __restrict__ emb, float* __restrict__ E,
    float* __restrict__ e2, unsigned short* __restrict__ EH,
    unsigned short* __restrict__ EL,
    const float* __restrict__ cnt, float* __restrict__ ncnt,
    const float* __restrict__ wiv, unsigned short* __restrict__ wTH,
    unsigned short* __restrict__ wTL) {
  __shared__ float tile[64][65];
  const int b = blockIdx.x;
  const int tid = threadIdx.x;
  if (b >= 2080) {               // transpose proj_inv_w [64][1024] -> [n][k]
    const int n0 = (b - 2080) * 64;
    const float4* w4 = (const float4*)wiv;
#pragma unroll
    for (int i = 0; i < 4; ++i) {
      int idx = tid + i * 256;
      int k = idx >> 4, nq = idx & 15;
      float4 v = w4[k * 256 + (n0 >> 2) + nq];
      tile[nq * 4 + 0][k] = v.x;
      tile[nq * 4 + 1][k] = v.y;
      tile[nq * 4 + 2][k] = v.z;
      tile[nq * 4 + 3][k] = v.w;
    }
    __syncthreads();
    const int n = tid >> 2;
    const int k0 = (tid & 3) * 16;
#pragma unroll
    for (int j = 0; j < 16; j += 4) {
      int k = k0 + j;
      float x0 = tile[n][k], x1 = tile[n][k + 1], x2 = tile[n][k + 2],
            x3 = tile[n][k + 3];
      unsigned short h0 = f2bf(x0), h1 = f2bf(x1), h2_ = f2bf(x2), h3 = f2bf(x3);
      uint2 hp_, lp_;
      hp_.x = (unsigned)h0 | ((unsigned)h1 << 16);
      hp_.y = (unsigned)h2_ | ((unsigned)h3 << 16);
      lp_.x = (unsigned)f2bf(x0 - bf2f(h0)) | ((unsigned)f2bf(x1 - bf2f(h1)) << 16);
      lp_.y = (unsigned)f2bf(x2 - bf2f(h2_)) | ((unsigned)f2bf(x3 - bf2f(h3)) << 16);
      size_t off = frag_off(n0 + n, k >> 4, (k >> 3) & 1) + (k & 7);
      *(uint2*)(wTH + off) = hp_;
      *(uint2*)(wTL + off) = lp_;
    }
    return;
  }
  if (b >= 2048) {               // new_count = count
    int i = (b - 2048) * 256 + tid;
    ncnt[i] = cnt[i];
    return;
  }
  const int c = b * 4 + (tid >> 6);
  const int lane = tid & 63;
  float v = emb[(size_t)c * 64 + lane];
  float sq = v * v;
#pragma unroll
  for (int o = 32; o > 0; o >>= 1) sq += __shfl_xor(sq, o, 64);
  float vn = v / sqrtf(sq);
  E[(size_t)c * 64 + lane] = vn;
  unsigned short hb = f2bf(vn);
  size_t off = frag_off(c, lane >> 4, (lane >> 3) & 1) + (lane & 7);
  EH[off] = hb;
  EL[off] = f2bf(vn - bf2f(hb));
  float s2 = vn * vn;
#pragma unroll
  for (int o = 32; o > 0; o >>= 1) s2 += __shfl_xor(s2, o, 64);
  if (lane == 0) e2[c] = s2;
}

// ---------------- Kernel 3: single-pass distance (argmin + top5) -----------
// grid (64 token-tiles, 8 code-strips), 512 threads (8 waves = 4 rowg x 2
// colg). 128 tokens resident in A-frags; streams 1024 codes in 16 chunks of
// 64 through one 16KB LDS buffer (reg-staged one chunk ahead). Per chunk:
// argmin update (u = e2c-2dot basis, monotone per row) + per-code top5 of
// the 128 resident tokens -> partial per (code, tile).
__global__ __launch_bounds__(512, 4) void k_dist(
    const unsigned short* __restrict__ hpH, const unsigned short* __restrict__ hpL,
    const unsigned short* __restrict__ EHg, const unsigned short* __restrict__ ELg,
    const float* __restrict__ h2g, const float* __restrict__ e2g,
    const float* __restrict__ maskg,
    float* __restrict__ amin_d, int* __restrict__ amin_c,
    float* __restrict__ t5d, unsigned char* __restrict__ t5o) {
  __shared__ __align__(16) unsigned char buf[16384];   // H [0,8K), L [8K,16K)
  __shared__ float e2l[1024];
  __shared__ float2 mpm[128];            // {m, h2*m + 1e7*(1-m)} per token
  __shared__ float sD[2][4][32][5];
  __shared__ int   sI[2][4][32][5];
  __shared__ float mD[2][128];
  __shared__ int   mC[2][128];
  const int tid = threadIdx.x;
  const int w = tid >> 6, lane = tid & 63;
  const int l31 = lane & 31, lh = lane >> 5;
  const int rowg = w >> 1, colg = w & 1;
  const int tok_base = blockIdx.x * 128;
  const int cstrip = blockIdx.y * 1024;
  // resident A fragments
  const int row_t = tok_base + rowg * 32 + l31;
  bf16x8 aH[4], aL[4];
#pragma unroll
  for (int ks = 0; ks < 4; ++ks) {
    aH[ks] = *(const bf16x8*)(hpH + frag_off(row_t, ks, lh));
    aL[ks] = *(const bf16x8*)(hpL + frag_off(row_t, ks, lh));
  }
  // stage e2 strip + per-token mask/pm
  e2l[tid] = e2g[cstrip + tid];
  e2l[tid + 512] = e2g[cstrip + tid + 512];
  if (tid < 128) {
    float m = maskg[tok_base + tid];
    float pm = fmaf(h2g[tok_base + tid], m, 1.0e7f * (1.f - m));
    mpm[tid] = make_float2(m, pm);
  }
  // argmin running state
  float bu[16]; int bc[16];
#pragma unroll
  for (int r = 0; r < 16; ++r) { bu[r] = FLT_MAX; bc[r] = 0x7fffffff; }
  // stage chunk 0 (16KB / 512 thr = one 16B H + one 16B L per thread)
  bf16x8 rH, rL;
  {
    size_t ge = (size_t)(blockIdx.y * 32) * 2048 + (size_t)tid * 8;
    rH = *(const bf16x8*)(EHg + ge);
    rL = *(const bf16x8*)(ELg + ge);
    *(bf16x8*)(buf + tid * 16) = rH;
    *(bf16x8*)(buf + 8192 + tid * 16) = rL;
  }
  __syncthreads();
  for (int ch = 0; ch < 16; ++ch) {
    if (ch < 15) {   // issue next chunk's loads; compute hides the latency
      size_t ge = (size_t)(blockIdx.y * 32 + (ch + 1) * 2) * 2048 + (size_t)tid * 8;
      rH = *(const bf16x8*)(EHg + ge);
      rL = *(const bf16x8*)(ELg + ge);
    }
    f32x16 acc = {};
#pragma unroll
    for (int ks = 0; ks < 4; ++ks) {
      const int boff = colg * 4096 + ((ks * 2 + lh) * 32 + l31) * 16;
      bf16x8 bL = *(const bf16x8*)(buf + 8192 + boff);
      bf16x8 bH = *(const bf16x8*)(buf + boff);
      acc = __builtin_amdgcn_mfma_f32_32x32x16_bf16(aL[ks], bL, acc, 0, 0, 0);
      acc = __builtin_amdgcn_mfma_f32_32x32x16_bf16(aL[ks], bH, acc, 0, 0, 0);
      acc = __builtin_amdgcn_mfma_f32_32x32x16_bf16(aH[ks], bL, acc, 0, 0, 0);
      acc = __builtin_amdgcn_mfma_f32_32x32x16_bf16(aH[ks], bH, acc, 0, 0, 0);
    }
    const int cs = cstrip + ch * 64;
    const int mycode = cs + colg * 32 + l31;
    const float e2c = e2l[ch * 64 + colg * 32 + l31];
    float td0 = FLT_MAX, td1 = FLT_MAX, td2 = FLT_MAX, td3 = FLT_MAX,
          td4 = FLT_MAX;
    int ti0 = 0x7fffffff, ti1 = 0x7fffffff, ti2 = 0x7fffffff,
        ti3 = 0x7fffffff, ti4 = 0x7fffffff;
#pragma unroll
    for (int r = 0; r < 16; ++r) {
      float u = fmaf(-2.f, acc[r], e2c);
      // argmin: codes ascend (chunks, then lanes merged lexicographic) ->
      // strict < keeps lowest code on exact ties; u-basis monotone per row.
      if (u < bu[r]) { bu[r] = u; bc[r] = mycode; }
      const int toff = rowg * 32 + (r & 3) + 8 * (r >> 2) + 4 * lh;  // asc in r
      float2 mp = mpm[toff];
      float dtp = fmaf(mp.x, u, mp.y);
      tins5(td0, td1, td2, td3, td4, ti0, ti1, ti2, ti3, ti4, dtp, toff);
    }
    // lane^32 merge (other lh rows, same code); snapshot first
    {
      float od0 = __shfl_xor(td0, 32, 64), od1 = __shfl_xor(td1, 32, 64),
            od2 = __shfl_xor(td2, 32, 64), od3 = __shfl_xor(td3, 32, 64),
            od4 = __shfl_xor(td4, 32, 64);
      int oi0 = __shfl_xor(ti0, 32, 64), oi1 = __shfl_xor(ti1, 32, 64),
          oi2 = __shfl_xor(ti2, 32, 64), oi3 = __shfl_xor(ti3, 32, 64),
          oi4 = __shfl_xor(ti4, 32, 64);
      lins5(td0, td1, td2, td3, td4, ti0, ti1, ti2, ti3, ti4, od0, oi0);
      lins5(td0, td1, td2, td3, td4, ti0, ti1, ti2, ti3, ti4, od1, oi1);
      lins5(td0, td1, td2, td3, td4, ti0, ti1, ti2, ti3, ti4, od2, oi2);
      lins5(td0, td1, td2, td3, td4, ti0, ti1, ti2, ti3, ti4, od3, oi3);
      lins5(td0, td1, td2, td3, td4, ti0, ti1, ti2, ti3, ti4, od4, oi4);
    }
    if (lane < 32) {
      sD[colg][rowg][l31][0] = td0; sD[colg][rowg][l31][1] = td1;
      sD[colg][rowg][l31][2] = td2; sD[colg][rowg][l31][3] = td3;
      sD[colg][rowg][l31][4] = td4;
      sI[colg][rowg][l31][0] = ti0; sI[colg][rowg][l31][1] = ti1;
      sI[colg][rowg][l31][2] = ti2; sI[colg][rowg][l31][3] = ti3;
      sI[colg][rowg][l31][4] = ti4;
    }
    __syncthreads();   // sD visible; all waves done reading buf
    if (tid < 64) {
      const int cg = tid >> 5, cl = tid & 31;
      float rd0 = sD[cg][0][cl][0], rd1 = sD[cg][0][cl][1],
            rd2 = sD[cg][0][cl][2], rd3 = sD[cg][0][cl][3],
            rd4 = sD[cg][0][cl][4];
      int ri0 = sI[cg][0][cl][0], ri1 = sI[cg][0][cl][1],
          ri2 = sI[cg][0][cl][2], ri3 = sI[cg][0][cl][3],
          ri4 = sI[cg][0][cl][4];
#pragma unroll
      for (int rw = 1; rw < 4; ++rw)
#pragma unroll
        for (int s = 0; s < 5; ++s)
          lins5(rd0, rd1, rd2, rd3, rd4, ri0, ri1, ri2, ri3, ri4,
                sD[cg][rw][cl][s], sI[cg][rw][cl][s]);
      const int code = cs + cg * 32 + cl;
      const size_t gb5 = ((size_t)blockIdx.x * 8192 + code) * 5;
      t5d[gb5 + 0] = rd0; t5d[gb5 + 1] = rd1; t5d[gb5 + 2] = rd2;
      t5d[gb5 + 3] = rd3; t5d[gb5 + 4] = rd4;
      t5o[gb5 + 0] = (unsigned char)ri0; t5o[gb5 + 1] = (unsigned char)ri1;
      t5o[gb5 + 2] = (unsigned char)ri2; t5o[gb5 + 3] = (unsigned char)ri3;
      t5o[gb5 + 4] = (unsigned char)ri4;
    }
    if (ch < 15) {   // overwrite buf with next chunk (everyone past reads)
      *(bf16x8*)(buf + tid * 16) = rH;
      *(bf16x8*)(buf + 8192 + tid * 16) = rL;
    }
    __syncthreads();   // buf ready; sD safe to rewrite
  }
  // argmin reduce across the 32 codes of each colg half
#pragma unroll
  for (int r = 0; r < 16; ++r) {
#pragma unroll
    for (int o = 1; o <= 16; o <<= 1) {
      float ou = __shfl_xor(bu[r], o, 64);
      int oc = __shfl_xor(bc[r], o, 64);
      if (ou < bu[r] || (ou == bu[r] && oc < bc[r])) { bu[r] = ou; bc[r] = oc; }
    }
  }
  if (l31 == 0) {
#pragma unroll
    for (int r = 0; r < 16; ++r) {
      const int roff = rowg * 32 + (r & 3) + 8 * (r >> 2) + 4 * lh;
      mD[colg][roff] = bu[r];
      mC[colg][roff] = bc[r];
    }
  }
  __syncthreads();
  if (tid < 128) {
    float d0 = mD[0][tid], d1 = mD[1][tid];
    int c0 = mC[0][tid], c1 = mC[1][tid];
    if (d1 < d0 || (d1 == d0 && c1 < c0)) { d0 = d1; c0 = c1; }
    const int t = tok_base + tid;
    amin_d[(size_t)t * 8 + blockIdx.y] = d0;
    amin_c[(size_t)t * 8 + blockIdx.y] = c0;
  }
}

// ---------------- Kernel 4: merge argmin, code, histogram, token loss ------
__global__ __launch_bounds__(256) void k_code(
    const float* __restrict__ amin_d, const int* __restrict__ amin_c,
    const float* __restrict__ hp, const float* __restrict__ E,
    const float* __restrict__ maskg,
    float* __restrict__ code_f, int* __restrict__ code_i,
    float* __restrict__ newcount, float* __restrict__ loss_tok) {
  const int wid = threadIdx.x >> 6;
  const int lane = threadIdx.x & 63;
  const int t = blockIdx.x * 4 + wid;
  float d = FLT_MAX;
  int c = 0x7fffffff;
  if (lane < 8) {
    d = amin_d[(size_t)t * 8 + lane];
    c = amin_c[(size_t)t * 8 + lane];
  }
#pragma unroll
  for (int o = 1; o <= 4; o <<= 1) {
    float od = __shfl_xor(d, o, 64);
    int oc = __shfl_xor(c, o, 64);
    if (od < d || (od == d && oc < c)) { d = od; c = oc; }
  }
  c = __shfl(c, 0, 64);
  if (maskg[t] == 0.f) c = 0;   // masked row: all dists 1e7 -> argmin = 0
  float a = hp[(size_t)t * 64 + lane];
  float e = E[(size_t)c * 64 + lane];
  float q = a + (e - a);
  float df = a - q;
  float ad = fabsf(df);
  float l = ad < 1.f ? 0.5f * df * df : ad - 0.5f;
#pragma unroll
  for (int o = 32; o > 0; o >>= 1) l += __shfl_xor(l, o, 64);
  if (lane == 0) {
    code_f[t] = (float)c;
    code_i[t] = c;
    loss_tok[t] = l;
    atomicAdd(&newcount[c], 1.0f);
  }
}

// ---------------- Kernel 5: q_out = E[code] @ proj_inv_w + b (MFMA) --------
__global__ __launch_bounds__(256, 2) void k_qout(
    const int* __restrict__ code_i,
    const unsigned short* __restrict__ EH, const unsigned short* __restrict__ EL,
    const unsigned short* __restrict__ wTH, const unsigned short* __restrict__ wTL,
    const float* __restrict__ bias, float* __restrict__ qout) {
  const int tid = threadIdx.x;
  const int w = tid >> 6, lane = tid & 63;
  const int l31 = lane & 31, lh = lane >> 5;
  const int rowg = w >> 1, colg = w & 1;
  const int tok_base = blockIdx.x * 64;
  const int col_base = blockIdx.y * 64;
  const int row_t = tok_base + rowg * 32 + l31;
  const int c = code_i[row_t];
  const int n = col_base + colg * 32 + l31;
  bf16x8 aH[4], aL[4], bH[4], bL[4];
#pragma unroll
  for (int ks = 0; ks < 4; ++ks) {
    aH[ks] = *(const bf16x8*)(EH + frag_off(c, ks, lh));
    aL[ks] = *(const bf16x8*)(EL + frag_off(c, ks, lh));
    bH[ks] = *(const bf16x8*)(wTH + frag_off(n, ks, lh));
    bL[ks] = *(const bf16x8*)(wTL + frag_off(n, ks, lh));
  }
  f32x16 c0 = {}, c1 = {}, c2 = {}, c3 = {};
#pragma unroll
  for (int ks = 0; ks < 4; ++ks) {
    c0 = __builtin_amdgcn_mfma_f32_32x32x16_bf16(aL[ks], bL[ks], c0, 0, 0, 0);
    c1 = __builtin_amdgcn_mfma_f32_32x32x16_bf16(aL[ks], bH[ks], c1, 0, 0, 0);
    c2 = __builtin_amdgcn_mfma_f32_32x32x16_bf16(aH[ks], bL[ks], c2, 0, 0, 0);
    c3 = __builtin_amdgcn_mfma_f32_32x32x16_bf16(aH[ks], bH[ks], c3, 0, 0, 0);
  }
  const float bc = bias[n];
#pragma unroll
  for (int r = 0; r < 16; ++r) {
    int row = rowg * 32 + (r & 3) + 8 * (r >> 2) + 4 * lh;
    float dot = ((c0[r] + c1[r]) + c2[r]) + c3[r];
    qout[(size_t)(tok_base + row) * 1024 + n] = dot + bc;
  }
}

// ---------------- Kernel 6: merge 64 tile-partials, EMA; block 128 = vq ----
__global__ __launch_bounds__(256) void k_emb(
    const float* __restrict__ t5d, const unsigned char* __restrict__ t5o,
    const float* __restrict__ hp, const float* __restrict__ E,
    float* __restrict__ newemb,
    const float* __restrict__ loss_tok, const float* __restrict__ maskg,
    float* __restrict__ vq) {
  __shared__ float S[256], M[256];
  __shared__ float wDs[4][64][5];
  __shared__ int   wIs[4][64][5];
  __shared__ int   selS[64][5];
  __shared__ float m5S[64];
  const int tid = threadIdx.x;
  if (blockIdx.x == 128) {       // vq_loss reduction
    float s = 0.f, m = 0.f;
    const int base = tid * 32;
    for (int i = 0; i < 32; ++i) {
      float mm = maskg[base + i];
      s = fmaf(loss_tok[base + i], mm, s);
      m += mm;
    }
    S[tid] = s; M[tid] = m;
    __syncthreads();
    if (tid == 0) {
      float tot = 0.f;
      for (int b = 0; b < 4; ++b) {
        float sb = 0.f, mb = 0.f;
        for (int i = 0; i < 64; ++i) { sb += S[b * 64 + i]; mb += M[b * 64 + i]; }
        tot += sb / mb;
      }
      vq[0] = tot * 1.25f / 256.0f;
    }
    return;
  }
  const int w = tid >> 6, lane = tid & 63;
  const int cb = blockIdx.x * 64;
  const int code = cb + lane;
  float e0 = FLT_MAX, e1 = FLT_MAX, e2_ = FLT_MAX, e3 = FLT_MAX, e4 = FLT_MAX;
  int j0 = 0x7fffffff, j1 = 0x7fffffff, j2 = 0x7fffffff, j3 = 0x7fffffff,
      j4 = 0x7fffffff;
  for (int t = w * 16; t < w * 16 + 16; ++t) {
    size_t eb = (size_t)t * 8192 + code;
    const float* dp = t5d + eb * 5;
    const unsigned char* op = t5o + eb * 5;
    lins5(e0, e1, e2_, e3, e4, j0, j1, j2, j3, j4, dp[0], t * 128 + op[0]);
    lins5(e0, e1, e2_, e3, e4, j0, j1, j2, j3, j4, dp[1], t * 128 + op[1]);
    lins5(e0, e1, e2_, e3, e4, j0, j1, j2, j3, j4, dp[2], t * 128 + op[2]);
    lins5(e0, e1, e2_, e3, e4, j0, j1, j2, j3, j4, dp[3], t * 128 + op[3]);
    lins5(e0, e1, e2_, e3, e4, j0, j1, j2, j3, j4, dp[4], t * 128 + op[4]);
  }
  wDs[w][lane][0] = e0; wDs[w][lane][1] = e1; wDs[w][lane][2] = e2_;
  wDs[w][lane][3] = e3; wDs[w][lane][4] = e4;
  wIs[w][lane][0] = j0; wIs[w][lane][1] = j1; wIs[w][lane][2] = j2;
  wIs[w][lane][3] = j3; wIs[w][lane][4] = j4;
  __syncthreads();
  if (tid < 64) {
    float r0 = wDs[0][tid][0], r1 = wDs[0][tid][1], r2 = wDs[0][tid][2],
          r3 = wDs[0][tid][3], r4 = wDs[0][tid][4];
    int q0 = wIs[0][tid][0], q1 = wIs[0][tid][1], q2 = wIs[0][tid][2],
        q3 = wIs[0][tid][3], q4 = wIs[0][tid][4];
#pragma unroll
    for (int rw = 1; rw < 4; ++rw)
#pragma unroll
      for (int s = 0; s < 5; ++s)
        lins5(r0, r1, r2, r3, r4, q0, q1, q2, q3, q4,
              wDs[rw][tid][s], wIs[rw][tid][s]);
    float m5 = fabsf(r0);
    m5 = fminf(m5, fabsf(r1)); m5 = fminf(m5, fabsf(r2));
    m5 = fminf(m5, fabsf(r3)); m5 = fminf(m5, fabsf(r4));
    selS[tid][0] = q0; selS[tid][1] = q1; selS[tid][2] = q2;
    selS[tid][3] = q3; selS[tid][4] = q4;
    m5S[tid] = m5;
  }
  __syncthreads();
#pragma unroll
  for (int cc = 0; cc < 16; ++cc) {
    const int cl = w + cc * 4;
    const int c = cb + cl;
    float hf = 0.f;
#pragma unroll
    for (int r = 0; r < 5; ++r) hf += hp[(size_t)selS[cl][r] * 64 + lane];
    hf = hf / 5.0f;
    float ev = E[(size_t)c * 64 + lane];
    float outv = (m5S[cl] > 0.1f) ? (ev * 0.995f + hf * (float)(1.0 - 0.995)) : ev;
    newemb[(size_t)c * 64 + lane] = outv;
  }
}

// ---------------------------------------------------------------------------
extern "C" void kernel_launch(void* const* d_in, const int* in_sizes, int n_in,
                              void* d_out, int out_size, void* d_ws,
                              size_t ws_size, hipStream_t stream) {
  (void)in_sizes; (void)n_in; (void)out_size; (void)ws_size;
  const float* h          = (const float*)d_in[0];
  const float* mask       = (const float*)d_in[1];
  const float* proj_w     = (const float*)d_in[2];
  const float* proj_b     = (const float*)d_in[3];
  const float* proj_inv_w = (const float*)d_in[4];
  const float* proj_inv_b = (const float*)d_in[5];
  const float* emb        = (const float*)d_in[6];
  const float* count      = (const float*)d_in[7];

  float* out      = (float*)d_out;
  float* q_out    = out;                 // 8388608
  float* code_f   = out + 8388608;       // 8192
  float* vq       = out + 8396800;       // 1
  float* newemb   = out + 8396801;       // 524288
  float* newcount = out + 8921089;       // 8192

  float* ws = (float*)d_ws;
  float* hp_norm        = ws;                                  // 524288
  float* h2             = ws + 524288;                         // 8192
  float* E              = ws + 532480;                         // 524288
  float* e2             = ws + 1056768;                        // 8192
  unsigned short* hpH   = (unsigned short*)(ws + 1064960);     // 262144 f
  unsigned short* hpL   = (unsigned short*)(ws + 1327104);     // 262144 f
  unsigned short* EH    = (unsigned short*)(ws + 1589248);     // 262144 f
  unsigned short* EL    = (unsigned short*)(ws + 1851392);     // 262144 f
  unsigned short* wTH   = (unsigned short*)(ws + 2113536);     // 32768 f
  unsigned short* wTL   = (unsigned short*)(ws + 2146304);     // 32768 f
  float* amin_d         = ws + 2179072;                        // 65536 (8192*8)
  int*   amin_c         = (int*)(ws + 2244608);                // 65536
  int*   code_i         = (int*)(ws + 2310144);                // 8192
  float* loss_tok       = ws + 2318336;                        // 8192
  float* t5d            = ws + 2326528;                        // 2621440 (64*8192*5)
  unsigned char* t5o    = (unsigned char*)(ws + 4947968);      // 163840 f (as u8)
  // total ~5.11M floats ~= 20.4 MB

  k_proj<<<512, 256, 0, stream>>>(h, proj_w, proj_b, hp_norm, h2, hpH, hpL);
  k_enorm<<<2096, 256, 0, stream>>>(emb, E, e2, EH, EL, count, newcount,
                                    proj_inv_w, wTH, wTL);
  k_dist<<<dim3(64, 8), 512, 0, stream>>>(hpH, hpL, EH, EL, h2, e2, mask,
                                          amin_d, amin_c, t5d, t5o);
  k_code<<<2048, 256, 0, stream>>>(amin_d, amin_c, hp_norm, E, mask,
                                   code_f, code_i, newcount, loss_tok);
  k_qout<<<dim3(128, 16), 256, 0, stream>>>(code_i, EH, EL, wTH, wTL,
                                            proj_inv_b, q_out);
  k_emb<<<129, 256, 0, stream>>>(t5d, t5o, hp_norm, E, newemb,
                                 loss_tok, mask, vq);
}

// Round 9
// 178.711 us; speedup vs baseline: 1.4791x; 1.4791x over previous
//
#include <hip/hip_runtime.h>
#include <float.h>

// ---------------------------------------------------------------------------
// VQ layer forward, MI355X. B=4, L=2048 (8192 tokens), D=1024, VQ_DIM=64,
// K_CODES=8192, EMA_K=5.
// Round 9: two distance kernels again (round-8 single-pass rebuilt top5 state
// per chunk = VALU sort kernel). Both kernels: 512 threads, streamed operand
// through double-buffered LDS (reg-staged, early-issued), frag-major
// coalesced everywhere, single MFMA chain, launch_bounds(512,4) (VGPR<=128).
// k_argmin: 128 tokens resident, codes stream, u-basis (no h2 needed).
// k_top5: 128 codes resident (lane's code fixed => top5 persists across
// chunks, filter rarely passes), tokens stream.
// ---------------------------------------------------------------------------

typedef __attribute__((ext_vector_type(8)))  short bf16x8;   // 8 bf16 = 4 VGPR
typedef __attribute__((ext_vector_type(16))) float f32x16;   // MFMA 32x32 acc

__device__ __forceinline__ unsigned short f2bf(float x) {
  unsigned u = __float_as_uint(x);
  unsigned r = (u + 0x7fffu + ((u >> 16) & 1u)) >> 16;   // RNE
  return (unsigned short)r;
}
__device__ __forceinline__ float bf2f(unsigned short b) {
  return __uint_as_float(((unsigned)b) << 16);
}
// fragment-major layout: entity-block(32) x ks(4) x lh(2) x lane(32) x 8 elems
__device__ __forceinline__ size_t frag_off(int e, int ks, int lh) {
  return ((size_t)((((e >> 5) * 4 + ks) * 2 + lh) * 32 + (e & 31))) * 8;
}

// sorted-5 insert, plain strict < (requires ascending-index insertion order)
__device__ __forceinline__ void tins5(float& d0, float& d1, float& d2,
                                      float& d3, float& d4, int& i0, int& i1,
                                      int& i2, int& i3, int& i4, float dv,
                                      int iv) {
  if (dv < d4) {
    d4 = dv; i4 = iv;
    if (d4 < d3) { float t = d3; d3 = d4; d4 = t; int u = i3; i3 = i4; i4 = u; }
    if (d3 < d2) { float t = d2; d2 = d3; d3 = t; int u = i2; i2 = i3; i3 = u; }
    if (d2 < d1) { float t = d1; d1 = d2; d2 = t; int u = i1; i1 = i2; i2 = u; }
    if (d1 < d0) { float t = d0; d0 = d1; d1 = t; int u = i0; i0 = i1; i1 = u; }
  }
}
// sorted-5 insert, lexicographic (d, idx) — order-independent merges
__device__ __forceinline__ void lins5(float& d0, float& d1, float& d2,
                                      float& d3, float& d4, int& i0, int& i1,
                                      int& i2, int& i3, int& i4, float dv,
                                      int iv) {
  if (dv < d4 || (dv == d4 && iv < i4)) {
    d4 = dv; i4 = iv;
    if (d4 < d3 || (d4 == d3 && i4 < i3)) { float t = d3; d3 = d4; d4 = t; int u = i3; i3 = i4; i4 = u; }
    if (d3 < d2 || (d3 == d2 && i3 < i2)) { float t = d2; d2 = d3; d3 = t; int u = i2; i2 = i3; i3 = u; }
    if (d2 < d1 || (d2 == d1 && i2 < i1)) { float t = d1; d1 = d2; d2 = t; int u = i1; i1 = i2; i2 = u; }
    if (d1 < d0 || (d1 == d0 && i1 < i0)) { float t = d0; d0 = d1; d1 = t; int u = i0; i0 = i1; i1 = u; }
  }
}

// ---------------- Kernel 1: hp = normalize(h @ proj_w + b), + bf16 split ---
__global__ __launch_bounds__(256) void k_proj(
    const float* __restrict__ h, const float* __restrict__ w,
    const float* __restrict__ bias, float* __restrict__ hp_norm,
    float* __restrict__ h2, unsigned short* __restrict__ hpH,
    unsigned short* __restrict__ hpL) {
  __shared__ __align__(16) float hs[16 * 68];   // 16 tok x 64 k (pad 68)
  __shared__ __align__(16) float ws[64 * 64];   // 64 k x 64 dim
  const int tid = threadIdx.x;
  const int tb = blockIdx.x * 16;
  const int tok = tid >> 4;
  const int dimg = tid & 15;
  const float4* h4 = (const float4*)h;
  const float4* w4 = (const float4*)w;
  float4* ws4 = (float4*)ws;
  float4 acc = {0.f, 0.f, 0.f, 0.f};
  for (int ch = 0; ch < 16; ++ch) {
    __syncthreads();
    *(float4*)&hs[tok * 68 + dimg * 4] = h4[(size_t)(tb + tok) * 256 + ch * 16 + dimg];
#pragma unroll
    for (int i = 0; i < 4; ++i) {
      int idx = tid + i * 256;
      int k = idx >> 4, dq = idx & 15;
      ws4[k * 16 + dq] = w4[(size_t)(ch * 64 + k) * 16 + dq];
    }
    __syncthreads();
#pragma unroll 8
    for (int k = 0; k < 64; ++k) {
      float hv = hs[tok * 68 + k];
      float4 wv = *(const float4*)&ws[k * 64 + dimg * 4];
      acc.x = fmaf(hv, wv.x, acc.x);
      acc.y = fmaf(hv, wv.y, acc.y);
      acc.z = fmaf(hv, wv.z, acc.z);
      acc.w = fmaf(hv, wv.w, acc.w);
    }
  }
  const float4 bv = ((const float4*)bias)[dimg];
  acc.x += bv.x; acc.y += bv.y; acc.z += bv.z; acc.w += bv.w;
  float sq = acc.x * acc.x + acc.y * acc.y + acc.z * acc.z + acc.w * acc.w;
#pragma unroll
  for (int o = 1; o <= 8; o <<= 1) sq += __shfl_xor(sq, o, 64);
  float nrm = sqrtf(sq);
  float4 vn;
  vn.x = acc.x / nrm; vn.y = acc.y / nrm; vn.z = acc.z / nrm; vn.w = acc.w / nrm;
  ((float4*)hp_norm)[(size_t)(tb + tok) * 16 + dimg] = vn;
  unsigned short hx = f2bf(vn.x), hy = f2bf(vn.y), hz = f2bf(vn.z), hw = f2bf(vn.w);
  uint2 hi_pack, lo_pack;
  hi_pack.x = (unsigned)hx | ((unsigned)hy << 16);
  hi_pack.y = (unsigned)hz | ((unsigned)hw << 16);
  lo_pack.x = (unsigned)f2bf(vn.x - bf2f(hx)) | ((unsigned)f2bf(vn.y - bf2f(hy)) << 16);
  lo_pack.y = (unsigned)f2bf(vn.z - bf2f(hz)) | ((unsigned)f2bf(vn.w - bf2f(hw)) << 16);
  {
    int ks = dimg >> 2, lh = (dimg >> 1) & 1, half = dimg & 1;
    size_t off = frag_off(tb + tok, ks, lh) + half * 4;
    *(uint2*)(hpH + off) = hi_pack;
    *(uint2*)(hpL + off) = lo_pack;
  }
  float s2 = vn.x * vn.x + vn.y * vn.y + vn.z * vn.z + vn.w * vn.w;
#pragma unroll
  for (int o = 1; o <= 8; o <<= 1) s2 += __shfl_xor(s2, o, 64);
  if (dimg == 0) h2[tb + tok] = s2;
}

// ---------------- Kernel 2: E-normalize + initcount + wT transpose ---------
// grid 2096: [0,2048) enorm, [2048,2080) newcount=count, [2080,2096) wT.
__global__ __launch_bounds__(256) void k_enorm(
    const float* __restrict__ emb, float* __restrict__ E,
    float* __restrict__ e2, unsigned short* __restrict__ EH,
    unsigned short* __restrict__ EL,
    const float* __restrict__ cnt, float* __restrict__ ncnt,
    const float* __restrict__ wiv, unsigned short* __restrict__ wTH,
    unsigned short* __restrict__ wTL) {
  __shared__ float tile[64][65];
  const int b = blockIdx.x;
  const int tid = threadIdx.x;
  if (b >= 2080) {               // transpose proj_inv_w [64][1024] -> [n][k]
    const int n0 = (b - 2080) * 64;
    const float4* w4 = (const float4*)wiv;
#pragma unroll
    for (int i = 0; i < 4; ++i) {
      int idx = tid + i * 256;
      int k = idx >> 4, nq = idx & 15;
      float4 v = w4[k * 256 + (n0 >> 2) + nq];
      tile[nq * 4 + 0][k] = v.x;
      tile[nq * 4 + 1][k] = v.y;
      tile[nq * 4 + 2][k] = v.z;
      tile[nq * 4 + 3][k] = v.w;
    }
    __syncthreads();
    const int n = tid >> 2;
    const int k0 = (tid & 3) * 16;
#pragma unroll
    for (int j = 0; j < 16; j += 4) {
      int k = k0 + j;
      float x0 = tile[n][k], x1 = tile[n][k + 1], x2 = tile[n][k + 2],
            x3 = tile[n][k + 3];
      unsigned short h0 = f2bf(x0), h1 = f2bf(x1), h2_ = f2bf(x2), h3 = f2bf(x3);
      uint2 hp_, lp_;
      hp_.x = (unsigned)h0 | ((unsigned)h1 << 16);
      hp_.y = (unsigned)h2_ | ((unsigned)h3 << 16);
      lp_.x = (unsigned)f2bf(x0 - bf2f(h0)) | ((unsigned)f2bf(x1 - bf2f(h1)) << 16);
      lp_.y = (unsigned)f2bf(x2 - bf2f(h2_)) | ((unsigned)f2bf(x3 - bf2f(h3)) << 16);
      size_t off = frag_off(n0 + n, k >> 4, (k >> 3) & 1) + (k & 7);
      *(uint2*)(wTH + off) = hp_;
      *(uint2*)(wTL + off) = lp_;
    }
    return;
  }
  if (b >= 2048) {               // new_count = count
    int i = (b - 2048) * 256 + tid;
    ncnt[i] = cnt[i];
    return;
  }
  const int c = b * 4 + (tid >> 6);
  const int lane = tid & 63;
  float v = emb[(size_t)c * 64 + lane];
  float sq = v * v;
#pragma unroll
  for (int o = 32; o > 0; o >>= 1) sq += __shfl_xor(sq, o, 64);
  float vn = v / sqrtf(sq);
  E[(size_t)c * 64 + lane] = vn;
  unsigned short hb = f2bf(vn);
  size_t off = frag_off(c, lane >> 4, (lane >> 3) & 1) + (lane & 7);
  EH[off] = hb;
  EL[off] = f2bf(vn - bf2f(hb));
  float s2 = vn * vn;
#pragma unroll
  for (int o = 32; o > 0; o >>= 1) s2 += __shfl_xor(s2, o, 64);
  if (lane == 0) e2[c] = s2;
}

// ---------------- Kernel 3a: argmin over codes (u-basis, LDS-streamed) -----
// grid (64 token-tiles, 8 code-strips), 512 thr = 8 waves (4 rowg x 2 colg).
// 128 tokens resident in A-frags; 1024 codes stream in 16 chunks of 64
// through double-buffered LDS (reg-staged, early-issued, 1 barrier/chunk).
__global__ __launch_bounds__(512, 4) void k_argmin(
    const unsigned short* __restrict__ hpH, const unsigned short* __restrict__ hpL,
    const unsigned short* __restrict__ EHg, const unsigned short* __restrict__ ELg,
    const float* __restrict__ e2g,
    float* __restrict__ amin_d, int* __restrict__ amin_c) {
  __shared__ __align__(16) unsigned char buf[2][16384];  // H [0,8K), L [8K,16K)
  __shared__ float e2l[1024];
  __shared__ float mD[2][128];
  __shared__ int   mC[2][128];
  const int tid = threadIdx.x;
  const int w = tid >> 6, lane = tid & 63;
  const int l31 = lane & 31, lh = lane >> 5;
  const int rowg = w >> 1, colg = w & 1;
  const int tok_base = blockIdx.x * 128;
  const int cstrip = blockIdx.y * 1024;
  const int row_t = tok_base + rowg * 32 + l31;
  bf16x8 aH[4], aL[4];
#pragma unroll
  for (int ks = 0; ks < 4; ++ks) {
    aH[ks] = *(const bf16x8*)(hpH + frag_off(row_t, ks, lh));
    aL[ks] = *(const bf16x8*)(hpL + frag_off(row_t, ks, lh));
  }
  e2l[tid] = e2g[cstrip + tid];
  e2l[tid + 512] = e2g[cstrip + tid + 512];
  float bu[16]; int bc[16];
#pragma unroll
  for (int r = 0; r < 16; ++r) { bu[r] = FLT_MAX; bc[r] = 0x7fffffff; }
  bf16x8 rH, rL;
  {
    size_t gb = (size_t)(blockIdx.y * 32) * 2048 + (size_t)tid * 8;
    rH = *(const bf16x8*)(EHg + gb);
    rL = *(const bf16x8*)(ELg + gb);
    *(bf16x8*)(buf[0] + tid * 16) = rH;
    *(bf16x8*)(buf[0] + 8192 + tid * 16) = rL;
  }
  __syncthreads();
  for (int ch = 0; ch < 16; ++ch) {
    if (ch < 15) {   // early-issue next chunk's loads; MFMA hides latency
      size_t gb = (size_t)(blockIdx.y * 32 + (ch + 1) * 2) * 2048 + (size_t)tid * 8;
      rH = *(const bf16x8*)(EHg + gb);
      rL = *(const bf16x8*)(ELg + gb);
    }
    const unsigned char* bcur = buf[ch & 1];
    f32x16 acc = {};
#pragma unroll
    for (int ks = 0; ks < 4; ++ks) {
      const int boff = ((colg * 8 + ks * 2 + lh) * 32 + l31) * 16;
      bf16x8 bL = *(const bf16x8*)(bcur + 8192 + boff);
      bf16x8 bH = *(const bf16x8*)(bcur + boff);
      acc = __builtin_amdgcn_mfma_f32_32x32x16_bf16(aL[ks], bL, acc, 0, 0, 0);
      acc = __builtin_amdgcn_mfma_f32_32x32x16_bf16(aL[ks], bH, acc, 0, 0, 0);
      acc = __builtin_amdgcn_mfma_f32_32x32x16_bf16(aH[ks], bL, acc, 0, 0, 0);
      acc = __builtin_amdgcn_mfma_f32_32x32x16_bf16(aH[ks], bH, acc, 0, 0, 0);
    }
    const int mycode = cstrip + ch * 64 + colg * 32 + l31;
    const float e2c = e2l[ch * 64 + colg * 32 + l31];
#pragma unroll
    for (int r = 0; r < 16; ++r) {
      // u = e2c - 2*dot; differs from d by +h2[token] (row-constant) ->
      // same argmin. Codes ascend across chunks: strict < keeps lowest.
      float u = fmaf(-2.f, acc[r], e2c);
      if (u < bu[r]) { bu[r] = u; bc[r] = mycode; }
    }
    if (ch < 15) {
      *(bf16x8*)(buf[(ch + 1) & 1] + tid * 16) = rH;
      *(bf16x8*)(buf[(ch + 1) & 1] + 8192 + tid * 16) = rL;
    }
    __syncthreads();
  }
#pragma unroll
  for (int r = 0; r < 16; ++r) {
#pragma unroll
    for (int o = 1; o <= 16; o <<= 1) {
      float ou = __shfl_xor(bu[r], o, 64);
      int oc = __shfl_xor(bc[r], o, 64);
      if (ou < bu[r] || (ou == bu[r] && oc < bc[r])) { bu[r] = ou; bc[r] = oc; }
    }
  }
  if (l31 == 0) {
#pragma unroll
    for (int r = 0; r < 16; ++r) {
      const int roff = rowg * 32 + (r & 3) + 8 * (r >> 2) + 4 * lh;
      mD[colg][roff] = bu[r];
      mC[colg][roff] = bc[r];
    }
  }
  __syncthreads();
  if (tid < 128) {
    float d0 = mD[0][tid], d1 = mD[1][tid];
    int c0 = mC[0][tid], c1 = mC[1][tid];
    if (d1 < d0 || (d1 == d0 && c1 < c0)) { d0 = d1; c0 = c1; }
    const int t = tok_base + tid;
    amin_d[(size_t)t * 8 + blockIdx.y] = d0;
    amin_c[(size_t)t * 8 + blockIdx.y] = c0;
  }
}

// ---------------- Kernel 3b: top-5 tokens per code (LDS-streamed) ----------
// grid (64 code-tiles, 8 token-strips), 512 thr = 8 waves (2 rowg x 4 colg).
// 128 codes resident in B-frags (lane's code fixed -> top5 persists across
// chunks, filter d<td4 rarely passes); 1024 tokens stream in 16 chunks of 64.
__global__ __launch_bounds__(512, 4) void k_top5(
    const unsigned short* __restrict__ hpH, const unsigned short* __restrict__ hpL,
    const unsigned short* __restrict__ EHg, const unsigned short* __restrict__ ELg,
    const float* __restrict__ h2g, const float* __restrict__ e2g,
    const float* __restrict__ maskg,
    float* __restrict__ t5d, int* __restrict__ t5i) {
  __shared__ __align__(16) unsigned char buf[2][16384];  // H [0,8K), L [8K,16K)
  __shared__ float Pm[1024];            // h2*m + 1e7*(1-m)
  __shared__ float Mm[1024];            // m
  __shared__ float sD[4][2][32][5];
  __shared__ int   sI[4][2][32][5];
  const int tid = threadIdx.x;
  const int w = tid >> 6, lane = tid & 63;
  const int l31 = lane & 31, lh = lane >> 5;
  const int rowg = w >> 2, colg = w & 3;
  const int code_t = blockIdx.x * 128 + colg * 32 + l31;   // resident code
  const int tstrip = blockIdx.y * 1024;
  bf16x8 bH[4], bL[4];
#pragma unroll
  for (int ks = 0; ks < 4; ++ks) {
    bH[ks] = *(const bf16x8*)(EHg + frag_off(code_t, ks, lh));
    bL[ks] = *(const bf16x8*)(ELg + frag_off(code_t, ks, lh));
  }
  const float e2c = e2g[code_t];
  {
    int t0 = tid, t1 = tid + 512;
    float m0 = maskg[tstrip + t0], m1 = maskg[tstrip + t1];
    Mm[t0] = m0; Mm[t1] = m1;
    Pm[t0] = fmaf(h2g[tstrip + t0], m0, 1.0e7f * (1.f - m0));
    Pm[t1] = fmaf(h2g[tstrip + t1], m1, 1.0e7f * (1.f - m1));
  }
  float td0 = FLT_MAX, td1 = FLT_MAX, td2 = FLT_MAX, td3 = FLT_MAX, td4 = FLT_MAX;
  int ti0 = 0x7fffffff, ti1 = 0x7fffffff, ti2 = 0x7fffffff, ti3 = 0x7fffffff,
      ti4 = 0x7fffffff;
  bf16x8 rH, rL;
  {
    size_t gb = (size_t)(blockIdx.y * 32) * 2048 + (size_t)tid * 8;
    rH = *(const bf16x8*)(hpH + gb);
    rL = *(const bf16x8*)(hpL + gb);
    *(bf16x8*)(buf[0] + tid * 16) = rH;
    *(bf16x8*)(buf[0] + 8192 + tid * 16) = rL;
  }
  __syncthreads();
  for (int ch = 0; ch < 16; ++ch) {
    if (ch < 15) {
      size_t gb = (size_t)(blockIdx.y * 32 + (ch + 1) * 2) * 2048 + (size_t)tid * 8;
      rH = *(const bf16x8*)(hpH + gb);
      rL = *(const bf16x8*)(hpL + gb);
    }
    const unsigned char* bcur = buf[ch & 1];
    f32x16 acc = {};
#pragma unroll
    for (int ks = 0; ks < 4; ++ks) {
      const int aoff = ((rowg * 8 + ks * 2 + lh) * 32 + l31) * 16;
      bf16x8 aL = *(const bf16x8*)(bcur + 8192 + aoff);
      bf16x8 aH = *(const bf16x8*)(bcur + aoff);
      acc = __builtin_amdgcn_mfma_f32_32x32x16_bf16(aL, bL[ks], acc, 0, 0, 0);
      acc = __builtin_amdgcn_mfma_f32_32x32x16_bf16(aL, bH[ks], acc, 0, 0, 0);
      acc = __builtin_amdgcn_mfma_f32_32x32x16_bf16(aH, bL[ks], acc, 0, 0, 0);
      acc = __builtin_amdgcn_mfma_f32_32x32x16_bf16(aH, bH[ks], acc, 0, 0, 0);
    }
    const int rowb = ch * 64 + rowg * 32 + 4 * lh;   // strip-local token base
#pragma unroll
    for (int r = 0; r < 16; ++r) {   // token ascending in r (fixed lh)
      const int toff = rowb + (r & 3) + 8 * (r >> 2);
      float u = fmaf(-2.f, acc[r], e2c);
      float d = fmaf(Mm[toff], u, Pm[toff]);
      if (d < td4)
        tins5(td0, td1, td2, td3, td4, ti0, ti1, ti2, ti3, ti4, d,
              tstrip + toff);
    }
    if (ch < 15) {
      *(bf16x8*)(buf[(ch + 1) & 1] + tid * 16) = rH;
      *(bf16x8*)(buf[(ch + 1) & 1] + 8192 + tid * 16) = rL;
    }
    __syncthreads();
  }
  // merge lane <-> lane^32 (other lh rows, same code); snapshot first
  {
    float od0 = __shfl_xor(td0, 32, 64), od1 = __shfl_xor(td1, 32, 64),
          od2 = __shfl_xor(td2, 32, 64), od3 = __shfl_xor(td3, 32, 64),
          od4 = __shfl_xor(td4, 32, 64);
    int oi0 = __shfl_xor(ti0, 32, 64), oi1 = __shfl_xor(ti1, 32, 64),
        oi2 = __shfl_xor(ti2, 32, 64), oi3 = __shfl_xor(ti3, 32, 64),
        oi4 = __shfl_xor(ti4, 32, 64);
    lins5(td0, td1, td2, td3, td4, ti0, ti1, ti2, ti3, ti4, od0, oi0);
    lins5(td0, td1, td2, td3, td4, ti0, ti1, ti2, ti3, ti4, od1, oi1);
    lins5(td0, td1, td2, td3, td4, ti0, ti1, ti2, ti3, ti4, od2, oi2);
    lins5(td0, td1, td2, td3, td4, ti0, ti1, ti2, ti3, ti4, od3, oi3);
    lins5(td0, td1, td2, td3, td4, ti0, ti1, ti2, ti3, ti4, od4, oi4);
  }
  if (lane < 32) {
    sD[colg][rowg][l31][0] = td0; sD[colg][rowg][l31][1] = td1;
    sD[colg][rowg][l31][2] = td2; sD[colg][rowg][l31][3] = td3;
    sD[colg][rowg][l31][4] = td4;
    sI[colg][rowg][l31][0] = ti0; sI[colg][rowg][l31][1] = ti1;
    sI[colg][rowg][l31][2] = ti2; sI[colg][rowg][l31][3] = ti3;
    sI[colg][rowg][l31][4] = ti4;
  }
  __syncthreads();
  if (tid < 128) {
    const int cg = tid >> 5, cl = tid & 31;
    float rd0 = sD[cg][0][cl][0], rd1 = sD[cg][0][cl][1],
          rd2 = sD[cg][0][cl][2], rd3 = sD[cg][0][cl][3],
          rd4 = sD[cg][0][cl][4];
    int ri0 = sI[cg][0][cl][0], ri1 = sI[cg][0][cl][1],
        ri2 = sI[cg][0][cl][2], ri3 = sI[cg][0][cl][3],
        ri4 = sI[cg][0][cl][4];
#pragma unroll
    for (int s = 0; s < 5; ++s)
      lins5(rd0, rd1, rd2, rd3, rd4, ri0, ri1, ri2, ri3, ri4,
            sD[cg][1][cl][s], sI[cg][1][cl][s]);
    const int code = blockIdx.x * 128 + tid;
    size_t gb = (size_t)code * 40 + (size_t)blockIdx.y * 5;
    t5d[gb + 0] = rd0; t5i[gb + 0] = ri0;
    t5d[gb + 1] = rd1; t5i[gb + 1] = ri1;
    t5d[gb + 2] = rd2; t5i[gb + 2] = ri2;
    t5d[gb + 3] = rd3; t5i[gb + 3] = ri3;
    t5d[gb + 4] = rd4; t5i[gb + 4] = ri4;
  }
}

// ---------------- Kernel 4: merge argmin, code, histogram, token loss ------
__global__ __launch_bounds__(256) void k_code(
    const float* __restrict__ amin_d, const int* __restrict__ amin_c,
    const float* __restrict__ hp, const float* __restrict__ E,
    const float* __restrict__ maskg,
    float* __restrict__ code_f, int* __restrict__ code_i,
    float* __restrict__ newcount, float* __restrict__ loss_tok) {
  const int wid = threadIdx.x >> 6;
  const int lane = threadIdx.x & 63;
  const int t = blockIdx.x * 4 + wid;
  float d = FLT_MAX;
  int c = 0x7fffffff;
  if (lane < 8) {
    d = amin_d[(size_t)t * 8 + lane];
    c = amin_c[(size_t)t * 8 + lane];
  }
#pragma unroll
  for (int o = 1; o <= 4; o <<= 1) {
    float od = __shfl_xor(d, o, 64);
    int oc = __shfl_xor(c, o, 64);
    if (od < d || (od == d && oc < c)) { d = od; c = oc; }
  }
  c = __shfl(c, 0, 64);
  if (maskg[t] == 0.f) c = 0;   // masked row: all dists 1e7 -> argmin = 0
  float a = hp[(size_t)t * 64 + lane];
  float e = E[(size_t)c * 64 + lane];
  float q = a + (e - a);
  float df = a - q;
  float ad = fabsf(df);
  float l = ad < 1.f ? 0.5f * df * df : ad - 0.5f;
#pragma unroll
  for (int o = 32; o > 0; o >>= 1) l += __shfl_xor(l, o, 64);
  if (lane == 0) {
    code_f[t] = (float)c;
    code_i[t] = c;
    loss_tok[t] = l;
    atomicAdd(&newcount[c], 1.0f);
  }
}

// ---------------- Kernel 5: q_out = E[code] @ proj_inv_w + b (MFMA) --------
__global__ __launch_bounds__(256, 2) void k_qout(
    const int* __restrict__ code_i,
    const unsigned short* __restrict__ EH, const unsigned short* __restrict__ EL,
    const unsigned short* __restrict__ wTH, const unsigned short* __restrict__ wTL,
    const float* __restrict__ bias, float* __restrict__ qout) {
  const int tid = threadIdx.x;
  const int w = tid >> 6, lane = tid & 63;
  const int l31 = lane & 31, lh = lane >> 5;
  const int rowg = w >> 1, colg = w & 1;
  const int tok_base = blockIdx.x * 64;
  const int col_base = blockIdx.y * 64;
  const int row_t = tok_base + rowg * 32 + l31;
  const int c = code_i[row_t];
  const int n = col_base + colg * 32 + l31;
  bf16x8 aH[4], aL[4], bH[4], bL[4];
#pragma unroll
  for (int ks = 0; ks < 4; ++ks) {
    aH[ks] = *(const bf16x8*)(EH + frag_off(c, ks, lh));
    aL[ks] = *(const bf16x8*)(EL + frag_off(c, ks, lh));
    bH[ks] = *(const bf16x8*)(wTH + frag_off(n, ks, lh));
    bL[ks] = *(const bf16x8*)(wTL + frag_off(n, ks, lh));
  }
  f32x16 c0 = {}, c1 = {}, c2 = {}, c3 = {};
#pragma unroll
  for (int ks = 0; ks < 4; ++ks) {
    c0 = __builtin_amdgcn_mfma_f32_32x32x16_bf16(aL[ks], bL[ks], c0, 0, 0, 0);
    c1 = __builtin_amdgcn_mfma_f32_32x32x16_bf16(aL[ks], bH[ks], c1, 0, 0, 0);
    c2 = __builtin_amdgcn_mfma_f32_32x32x16_bf16(aH[ks], bL[ks], c2, 0, 0, 0);
    c3 = __builtin_amdgcn_mfma_f32_32x32x16_bf16(aH[ks], bH[ks], c3, 0, 0, 0);
  }
  const float bc = bias[n];
#pragma unroll
  for (int r = 0; r < 16; ++r) {
    int row = rowg * 32 + (r & 3) + 8 * (r >> 2) + 4 * lh;
    float dot = ((c0[r] + c1[r]) + c2[r]) + c3[r];
    qout[(size_t)(tok_base + row) * 1024 + n] = dot + bc;
  }
}

// ---------------- Kernel 6: merge top5 + EMA update; block 2048 = vq_loss --
__global__ __launch_bounds__(256) void k_emb(
    const float* __restrict__ t5d, const int* __restrict__ t5i,
    const float* __restrict__ hp, const float* __restrict__ E,
    float* __restrict__ newemb,
    const float* __restrict__ loss_tok, const float* __restrict__ maskg,
    float* __restrict__ vq) {
  __shared__ float S[256], M[256];
  const int tid = threadIdx.x;
  if (blockIdx.x == 2048) {      // vq_loss reduction
    float s = 0.f, m = 0.f;
    const int base = tid * 32;
    for (int i = 0; i < 32; ++i) {
      float mm = maskg[base + i];
      s = fmaf(loss_tok[base + i], mm, s);
      m += mm;
    }
    S[tid] = s; M[tid] = m;
    __syncthreads();
    if (tid == 0) {
      float tot = 0.f;
      for (int b = 0; b < 4; ++b) {
        float sb = 0.f, mb = 0.f;
        for (int i = 0; i < 64; ++i) { sb += S[b * 64 + i]; mb += M[b * 64 + i]; }
        tot += sb / mb;
      }
      vq[0] = tot * 1.25f / 256.0f;
    }
    return;
  }
  const int wid = tid >> 6;
  const int lane = tid & 63;
  const int c = blockIdx.x * 4 + wid;
  float d = FLT_MAX;
  int idx = 0x7fffffff;
  if (lane < 40) {
    d = t5d[(size_t)c * 40 + lane];
    idx = t5i[(size_t)c * 40 + lane];
  }
  float seld[5]; int sel[5];
#pragma unroll
  for (int r = 0; r < 5; ++r) {
    float bd = d; int bi = idx;
#pragma unroll
    for (int o = 1; o <= 32; o <<= 1) {
      float od = __shfl_xor(bd, o, 64);
      int oi = __shfl_xor(bi, o, 64);
      if (od < bd || (od == bd && oi < bi)) { bd = od; bi = oi; }
    }
    seld[r] = bd; sel[r] = bi;
    if (idx == bi) d = FLT_MAX;   // token ids unique across strips
  }
  float m5 = fabsf(seld[0]);
#pragma unroll
  for (int r = 1; r < 5; ++r) m5 = fminf(m5, fabsf(seld[r]));
  float hf = 0.f;
#pragma unroll
  for (int r = 0; r < 5; ++r) hf += hp[(size_t)sel[r] * 64 + lane];
  hf = hf / 5.0f;
  float ev = E[(size_t)c * 64 + lane];
  float outv = (m5 > 0.1f) ? (ev * 0.995f + hf * (float)(1.0 - 0.995)) : ev;
  newemb[(size_t)c * 64 + lane] = outv;
}

// ---------------------------------------------------------------------------
extern "C" void kernel_launch(void* const* d_in, const int* in_sizes, int n_in,
                              void* d_out, int out_size, void* d_ws,
                              size_t ws_size, hipStream_t stream) {
  (void)in_sizes; (void)n_in; (void)out_size; (void)ws_size;
  const float* h          = (const float*)d_in[0];
  const float* mask       = (const float*)d_in[1];
  const float* proj_w     = (const float*)d_in[2];
  const float* proj_b     = (const float*)d_in[3];
  const float* proj_inv_w = (const float*)d_in[4];
  const float* proj_inv_b = (const float*)d_in[5];
  const float* emb        = (const float*)d_in[6];
  const float* count      = (const float*)d_in[7];

  float* out      = (float*)d_out;
  float* q_out    = out;                 // 8388608
  float* code_f   = out + 8388608;       // 8192
  float* vq       = out + 8396800;       // 1
  float* newemb   = out + 8396801;       // 524288
  float* newcount = out + 8921089;       // 8192

  float* ws = (float*)d_ws;
  float* hp_norm        = ws;                                  // 524288
  float* h2             = ws + 524288;                         // 8192
  float* E              = ws + 532480;                         // 524288
  float* e2             = ws + 1056768;                        // 8192
  unsigned short* hpH   = (unsigned short*)(ws + 1064960);     // 262144 f
  unsigned short* hpL   = (unsigned short*)(ws + 1327104);     // 262144 f
  unsigned short* EH    = (unsigned short*)(ws + 1589248);     // 262144 f
  unsigned short* EL    = (unsigned short*)(ws + 1851392);     // 262144 f
  unsigned short* wTH   = (unsigned short*)(ws + 2113536);     // 32768 f
  unsigned short* wTL   = (unsigned short*)(ws + 2146304);     // 32768 f
  float* amin_d         = ws + 2179072;                        // 65536 (8192*8)
  int*   amin_c         = (int*)(ws + 2244608);                // 65536
  int*   code_i         = (int*)(ws + 2310144);                // 8192
  float* t5d            = ws + 2318336;                        // 327680 (8192*40)
  int*   t5i            = (int*)(ws + 2646016);                // 327680
  float* loss_tok       = ws + 2973696;                        // 8192

  k_proj<<<512, 256, 0, stream>>>(h, proj_w, proj_b, hp_norm, h2, hpH, hpL);
  k_enorm<<<2096, 256, 0, stream>>>(emb, E, e2, EH, EL, count, newcount,
                                    proj_inv_w, wTH, wTL);
  k_argmin<<<dim3(64, 8), 512, 0, stream>>>(hpH, hpL, EH, EL, e2,
                                            amin_d, amin_c);
  k_top5<<<dim3(64, 8), 512, 0, stream>>>(hpH, hpL, EH, EL, h2, e2, mask,
                                          t5d, t5i);
  k_code<<<2048, 256, 0, stream>>>(amin_d, amin_c, hp_norm, E, mask,
                                   code_f, code_i, newcount, loss_tok);
  k_qout<<<dim3(128, 16), 256, 0, stream>>>(code_i, EH, EL, wTH, wTL,
                                            proj_inv_b, q_out);
  k_emb<<<2049, 256, 0, stream>>>(t5d, t5i, hp_norm, E, newemb,
                                  loss_tok, mask, vq);
}

// Round 10
// 172.759 us; speedup vs baseline: 1.5301x; 1.0345x over previous
//
#include <hip/hip_runtime.h>
#include <float.h>

// ---------------------------------------------------------------------------
// VQ layer forward, MI355X. B=4, L=2048 (8192 tokens), D=1024, VQ_DIM=64,
// K_CODES=8192, EMA_K=5.
// Round 10: k_top5 epilogue slimmed. Round-9 counters: VALUBusy 82%,
// MfmaUtil 17.5% -> per-element cost (2 fmaf + 2 scalar LDS reads + branch)
// dominated. Now: kappa-basis ranking (kappa = Pm[t] - 2*dot; d = kappa+e2c
// applied once at write-out -- order-identical per code), Pm read as float4
// per rq-quad (16 ds_read_b32 -> 4 ds_read_b128 per chunk), Mm deleted.
// Rest identical to round-9 (178.7 us) winner.
// ---------------------------------------------------------------------------

typedef __attribute__((ext_vector_type(8)))  short bf16x8;   // 8 bf16 = 4 VGPR
typedef __attribute__((ext_vector_type(16))) float f32x16;   // MFMA 32x32 acc

__device__ __forceinline__ unsigned short f2bf(float x) {
  unsigned u = __float_as_uint(x);
  unsigned r = (u + 0x7fffu + ((u >> 16) & 1u)) >> 16;   // RNE
  return (unsigned short)r;
}
__device__ __forceinline__ float bf2f(unsigned short b) {
  return __uint_as_float(((unsigned)b) << 16);
}
// fragment-major layout: entity-block(32) x ks(4) x lh(2) x lane(32) x 8 elems
__device__ __forceinline__ size_t frag_off(int e, int ks, int lh) {
  return ((size_t)((((e >> 5) * 4 + ks) * 2 + lh) * 32 + (e & 31))) * 8;
}

// sorted-5 insert, plain strict < (requires ascending-index insertion order)
__device__ __forceinline__ void tins5(float& d0, float& d1, float& d2,
                                      float& d3, float& d4, int& i0, int& i1,
                                      int& i2, int& i3, int& i4, float dv,
                                      int iv) {
  if (dv < d4) {
    d4 = dv; i4 = iv;
    if (d4 < d3) { float t = d3; d3 = d4; d4 = t; int u = i3; i3 = i4; i4 = u; }
    if (d3 < d2) { float t = d2; d2 = d3; d3 = t; int u = i2; i2 = i3; i3 = u; }
    if (d2 < d1) { float t = d1; d1 = d2; d2 = t; int u = i1; i1 = i2; i2 = u; }
    if (d1 < d0) { float t = d0; d0 = d1; d1 = t; int u = i0; i0 = i1; i1 = u; }
  }
}
// sorted-5 insert, lexicographic (d, idx) — order-independent merges
__device__ __forceinline__ void lins5(float& d0, float& d1, float& d2,
                                      float& d3, float& d4, int& i0, int& i1,
                                      int& i2, int& i3, int& i4, float dv,
                                      int iv) {
  if (dv < d4 || (dv == d4 && iv < i4)) {
    d4 = dv; i4 = iv;
    if (d4 < d3 || (d4 == d3 && i4 < i3)) { float t = d3; d3 = d4; d4 = t; int u = i3; i3 = i4; i4 = u; }
    if (d3 < d2 || (d3 == d2 && i3 < i2)) { float t = d2; d2 = d3; d3 = t; int u = i2; i2 = i3; i3 = u; }
    if (d2 < d1 || (d2 == d1 && i2 < i1)) { float t = d1; d1 = d2; d2 = t; int u = i1; i1 = i2; i2 = u; }
    if (d1 < d0 || (d1 == d0 && i1 < i0)) { float t = d0; d0 = d1; d1 = t; int u = i0; i0 = i1; i1 = u; }
  }
}

// ---------------- Kernel 1: hp = normalize(h @ proj_w + b), + bf16 split ---
__global__ __launch_bounds__(256) void k_proj(
    const float* __restrict__ h, const float* __restrict__ w,
    const float* __restrict__ bias, float* __restrict__ hp_norm,
    float* __restrict__ h2, unsigned short* __restrict__ hpH,
    unsigned short* __restrict__ hpL) {
  __shared__ __align__(16) float hs[16 * 68];   // 16 tok x 64 k (pad 68)
  __shared__ __align__(16) float ws[64 * 64];   // 64 k x 64 dim
  const int tid = threadIdx.x;
  const int tb = blockIdx.x * 16;
  const int tok = tid >> 4;
  const int dimg = tid & 15;
  const float4* h4 = (const float4*)h;
  const float4* w4 = (const float4*)w;
  float4* ws4 = (float4*)ws;
  float4 acc = {0.f, 0.f, 0.f, 0.f};
  for (int ch = 0; ch < 16; ++ch) {
    __syncthreads();
    *(float4*)&hs[tok * 68 + dimg * 4] = h4[(size_t)(tb + tok) * 256 + ch * 16 + dimg];
#pragma unroll
    for (int i = 0; i < 4; ++i) {
      int idx = tid + i * 256;
      int k = idx >> 4, dq = idx & 15;
      ws4[k * 16 + dq] = w4[(size_t)(ch * 64 + k) * 16 + dq];
    }
    __syncthreads();
#pragma unroll 8
    for (int k = 0; k < 64; ++k) {
      float hv = hs[tok * 68 + k];
      float4 wv = *(const float4*)&ws[k * 64 + dimg * 4];
      acc.x = fmaf(hv, wv.x, acc.x);
      acc.y = fmaf(hv, wv.y, acc.y);
      acc.z = fmaf(hv, wv.z, acc.z);
      acc.w = fmaf(hv, wv.w, acc.w);
    }
  }
  const float4 bv = ((const float4*)bias)[dimg];
  acc.x += bv.x; acc.y += bv.y; acc.z += bv.z; acc.w += bv.w;
  float sq = acc.x * acc.x + acc.y * acc.y + acc.z * acc.z + acc.w * acc.w;
#pragma unroll
  for (int o = 1; o <= 8; o <<= 1) sq += __shfl_xor(sq, o, 64);
  float nrm = sqrtf(sq);
  float4 vn;
  vn.x = acc.x / nrm; vn.y = acc.y / nrm; vn.z = acc.z / nrm; vn.w = acc.w / nrm;
  ((float4*)hp_norm)[(size_t)(tb + tok) * 16 + dimg] = vn;
  unsigned short hx = f2bf(vn.x), hy = f2bf(vn.y), hz = f2bf(vn.z), hw = f2bf(vn.w);
  uint2 hi_pack, lo_pack;
  hi_pack.x = (unsigned)hx | ((unsigned)hy << 16);
  hi_pack.y = (unsigned)hz | ((unsigned)hw << 16);
  lo_pack.x = (unsigned)f2bf(vn.x - bf2f(hx)) | ((unsigned)f2bf(vn.y - bf2f(hy)) << 16);
  lo_pack.y = (unsigned)f2bf(vn.z - bf2f(hz)) | ((unsigned)f2bf(vn.w - bf2f(hw)) << 16);
  {
    int ks = dimg >> 2, lh = (dimg >> 1) & 1, half = dimg & 1;
    size_t off = frag_off(tb + tok, ks, lh) + half * 4;
    *(uint2*)(hpH + off) = hi_pack;
    *(uint2*)(hpL + off) = lo_pack;
  }
  float s2 = vn.x * vn.x + vn.y * vn.y + vn.z * vn.z + vn.w * vn.w;
#pragma unroll
  for (int o = 1; o <= 8; o <<= 1) s2 += __shfl_xor(s2, o, 64);
  if (dimg == 0) h2[tb + tok] = s2;
}

// ---------------- Kernel 2: E-normalize + initcount + wT transpose ---------
// grid 2096: [0,2048) enorm, [2048,2080) newcount=count, [2080,2096) wT.
__global__ __launch_bounds__(256) void k_enorm(
    const float* __restrict__ emb, float* __restrict__ E,
    float* __restrict__ e2, unsigned short* __restrict__ EH,
    unsigned short* __restrict__ EL,
    const float* __restrict__ cnt, float* __restrict__ ncnt,
    const float* __restrict__ wiv, unsigned short* __restrict__ wTH,
    unsigned short* __restrict__ wTL) {
  __shared__ float tile[64][65];
  const int b = blockIdx.x;
  const int tid = threadIdx.x;
  if (b >= 2080) {               // transpose proj_inv_w [64][1024] -> [n][k]
    const int n0 = (b - 2080) * 64;
    const float4* w4 = (const float4*)wiv;
#pragma unroll
    for (int i = 0; i < 4; ++i) {
      int idx = tid + i * 256;
      int k = idx >> 4, nq = idx & 15;
      float4 v = w4[k * 256 + (n0 >> 2) + nq];
      tile[nq * 4 + 0][k] = v.x;
      tile[nq * 4 + 1][k] = v.y;
      tile[nq * 4 + 2][k] = v.z;
      tile[nq * 4 + 3][k] = v.w;
    }
    __syncthreads();
    const int n = tid >> 2;
    const int k0 = (tid & 3) * 16;
#pragma unroll
    for (int j = 0; j < 16; j += 4) {
      int k = k0 + j;
      float x0 = tile[n][k], x1 = tile[n][k + 1], x2 = tile[n][k + 2],
            x3 = tile[n][k + 3];
      unsigned short h0 = f2bf(x0), h1 = f2bf(x1), h2_ = f2bf(x2), h3 = f2bf(x3);
      uint2 hp_, lp_;
      hp_.x = (unsigned)h0 | ((unsigned)h1 << 16);
      hp_.y = (unsigned)h2_ | ((unsigned)h3 << 16);
      lp_.x = (unsigned)f2bf(x0 - bf2f(h0)) | ((unsigned)f2bf(x1 - bf2f(h1)) << 16);
      lp_.y = (unsigned)f2bf(x2 - bf2f(h2_)) | ((unsigned)f2bf(x3 - bf2f(h3)) << 16);
      size_t off = frag_off(n0 + n, k >> 4, (k >> 3) & 1) + (k & 7);
      *(uint2*)(wTH + off) = hp_;
      *(uint2*)(wTL + off) = lp_;
    }
    return;
  }
  if (b >= 2048) {               // new_count = count
    int i = (b - 2048) * 256 + tid;
    ncnt[i] = cnt[i];
    return;
  }
  const int c = b * 4 + (tid >> 6);
  const int lane = tid & 63;
  float v = emb[(size_t)c * 64 + lane];
  float sq = v * v;
#pragma unroll
  for (int o = 32; o > 0; o >>= 1) sq += __shfl_xor(sq, o, 64);
  float vn = v / sqrtf(sq);
  E[(size_t)c * 64 + lane] = vn;
  unsigned short hb = f2bf(vn);
  size_t off = frag_off(c, lane >> 4, (lane >> 3) & 1) + (lane & 7);
  EH[off] = hb;
  EL[off] = f2bf(vn - bf2f(hb));
  float s2 = vn * vn;
#pragma unroll
  for (int o = 32; o > 0; o >>= 1) s2 += __shfl_xor(s2, o, 64);
  if (lane == 0) e2[c] = s2;
}

// ---------------- Kernel 3a: argmin over codes (u-basis, LDS-streamed) -----
// grid (64 token-tiles, 8 code-strips), 512 thr = 8 waves (4 rowg x 2 colg).
__global__ __launch_bounds__(512, 4) void k_argmin(
    const unsigned short* __restrict__ hpH, const unsigned short* __restrict__ hpL,
    const unsigned short* __restrict__ EHg, const unsigned short* __restrict__ ELg,
    const float* __restrict__ e2g,
    float* __restrict__ amin_d, int* __restrict__ amin_c) {
  __shared__ __align__(16) unsigned char buf[2][16384];  // H [0,8K), L [8K,16K)
  __shared__ float e2l[1024];
  __shared__ float mD[2][128];
  __shared__ int   mC[2][128];
  const int tid = threadIdx.x;
  const int w = tid >> 6, lane = tid & 63;
  const int l31 = lane & 31, lh = lane >> 5;
  const int rowg = w >> 1, colg = w & 1;
  const int tok_base = blockIdx.x * 128;
  const int cstrip = blockIdx.y * 1024;
  const int row_t = tok_base + rowg * 32 + l31;
  bf16x8 aH[4], aL[4];
#pragma unroll
  for (int ks = 0; ks < 4; ++ks) {
    aH[ks] = *(const bf16x8*)(hpH + frag_off(row_t, ks, lh));
    aL[ks] = *(const bf16x8*)(hpL + frag_off(row_t, ks, lh));
  }
  e2l[tid] = e2g[cstrip + tid];
  e2l[tid + 512] = e2g[cstrip + tid + 512];
  float bu[16]; int bc[16];
#pragma unroll
  for (int r = 0; r < 16; ++r) { bu[r] = FLT_MAX; bc[r] = 0x7fffffff; }
  bf16x8 rH, rL;
  {
    size_t gb = (size_t)(blockIdx.y * 32) * 2048 + (size_t)tid * 8;
    rH = *(const bf16x8*)(EHg + gb);
    rL = *(const bf16x8*)(ELg + gb);
    *(bf16x8*)(buf[0] + tid * 16) = rH;
    *(bf16x8*)(buf[0] + 8192 + tid * 16) = rL;
  }
  __syncthreads();
  for (int ch = 0; ch < 16; ++ch) {
    if (ch < 15) {   // early-issue next chunk's loads; MFMA hides latency
      size_t gb = (size_t)(blockIdx.y * 32 + (ch + 1) * 2) * 2048 + (size_t)tid * 8;
      rH = *(const bf16x8*)(EHg + gb);
      rL = *(const bf16x8*)(ELg + gb);
    }
    const unsigned char* bcur = buf[ch & 1];
    f32x16 acc = {};
#pragma unroll
    for (int ks = 0; ks < 4; ++ks) {
      const int boff = ((colg * 8 + ks * 2 + lh) * 32 + l31) * 16;
      bf16x8 bL = *(const bf16x8*)(bcur + 8192 + boff);
      bf16x8 bH = *(const bf16x8*)(bcur + boff);
      acc = __builtin_amdgcn_mfma_f32_32x32x16_bf16(aL[ks], bL, acc, 0, 0, 0);
      acc = __builtin_amdgcn_mfma_f32_32x32x16_bf16(aL[ks], bH, acc, 0, 0, 0);
      acc = __builtin_amdgcn_mfma_f32_32x32x16_bf16(aH[ks], bL, acc, 0, 0, 0);
      acc = __builtin_amdgcn_mfma_f32_32x32x16_bf16(aH[ks], bH, acc, 0, 0, 0);
    }
    const int mycode = cstrip + ch * 64 + colg * 32 + l31;
    const float e2c = e2l[ch * 64 + colg * 32 + l31];
#pragma unroll
    for (int r = 0; r < 16; ++r) {
      // u = e2c - 2*dot; differs from d by +h2[token] (row-constant) ->
      // same argmin. Codes ascend across chunks: strict < keeps lowest.
      float u = fmaf(-2.f, acc[r], e2c);
      if (u < bu[r]) { bu[r] = u; bc[r] = mycode; }
    }
    if (ch < 15) {
      *(bf16x8*)(buf[(ch + 1) & 1] + tid * 16) = rH;
      *(bf16x8*)(buf[(ch + 1) & 1] + 8192 + tid * 16) = rL;
    }
    __syncthreads();
  }
#pragma unroll
  for (int r = 0; r < 16; ++r) {
#pragma unroll
    for (int o = 1; o <= 16; o <<= 1) {
      float ou = __shfl_xor(bu[r], o, 64);
      int oc = __shfl_xor(bc[r], o, 64);
      if (ou < bu[r] || (ou == bu[r] && oc < bc[r])) { bu[r] = ou; bc[r] = oc; }
    }
  }
  if (l31 == 0) {
#pragma unroll
    for (int r = 0; r < 16; ++r) {
      const int roff = rowg * 32 + (r & 3) + 8 * (r >> 2) + 4 * lh;
      mD[colg][roff] = bu[r];
      mC[colg][roff] = bc[r];
    }
  }
  __syncthreads();
  if (tid < 128) {
    float d0 = mD[0][tid], d1 = mD[1][tid];
    int c0 = mC[0][tid], c1 = mC[1][tid];
    if (d1 < d0 || (d1 == d0 && c1 < c0)) { d0 = d1; c0 = c1; }
    const int t = tok_base + tid;
    amin_d[(size_t)t * 8 + blockIdx.y] = d0;
    amin_c[(size_t)t * 8 + blockIdx.y] = c0;
  }
}

// ---------------- Kernel 3b: top-5 tokens per code (kappa-basis) -----------
// grid (64 code-tiles, 8 token-strips), 512 thr = 8 waves (2 rowg x 4 colg).
// 128 codes resident in B-frags; 1024 tokens stream in 16 chunks of 64.
// Ranking key kappa = Pm[t] - 2*dot (Pm = m*h2 + 1e7*(1-m)); d = kappa + e2c
// applied once at write-out (e2c constant per code -> order-identical).
__global__ __launch_bounds__(512, 4) void k_top5(
    const unsigned short* __restrict__ hpH, const unsigned short* __restrict__ hpL,
    const unsigned short* __restrict__ EHg, const unsigned short* __restrict__ ELg,
    const float* __restrict__ h2g, const float* __restrict__ e2g,
    const float* __restrict__ maskg,
    float* __restrict__ t5d, int* __restrict__ t5i) {
  __shared__ __align__(16) unsigned char buf[2][16384];  // H [0,8K), L [8K,16K)
  __shared__ __align__(16) float Pl[1024];   // m*h2 + 1e7*(1-m)
  __shared__ float sD[4][2][32][5];
  __shared__ int   sI[4][2][32][5];
  const int tid = threadIdx.x;
  const int w = tid >> 6, lane = tid & 63;
  const int l31 = lane & 31, lh = lane >> 5;
  const int rowg = w >> 2, colg = w & 3;
  const int code_t = blockIdx.x * 128 + colg * 32 + l31;   // resident code
  const int tstrip = blockIdx.y * 1024;
  bf16x8 bH[4], bL[4];
#pragma unroll
  for (int ks = 0; ks < 4; ++ks) {
    bH[ks] = *(const bf16x8*)(EHg + frag_off(code_t, ks, lh));
    bL[ks] = *(const bf16x8*)(ELg + frag_off(code_t, ks, lh));
  }
  {
    int t0 = tid, t1 = tid + 512;
    float m0 = maskg[tstrip + t0], m1 = maskg[tstrip + t1];
    Pl[t0] = fmaf(h2g[tstrip + t0], m0, 1.0e7f * (1.f - m0));
    Pl[t1] = fmaf(h2g[tstrip + t1], m1, 1.0e7f * (1.f - m1));
  }
  float td0 = FLT_MAX, td1 = FLT_MAX, td2 = FLT_MAX, td3 = FLT_MAX, td4 = FLT_MAX;
  int ti0 = 0x7fffffff, ti1 = 0x7fffffff, ti2 = 0x7fffffff, ti3 = 0x7fffffff,
      ti4 = 0x7fffffff;
  bf16x8 rH, rL;
  {
    size_t gb = (size_t)(blockIdx.y * 32) * 2048 + (size_t)tid * 8;
    rH = *(const bf16x8*)(hpH + gb);
    rL = *(const bf16x8*)(hpL + gb);
    *(bf16x8*)(buf[0] + tid * 16) = rH;
    *(bf16x8*)(buf[0] + 8192 + tid * 16) = rL;
  }
  __syncthreads();
  for (int ch = 0; ch < 16; ++ch) {
    if (ch < 15) {
      size_t gb = (size_t)(blockIdx.y * 32 + (ch + 1) * 2) * 2048 + (size_t)tid * 8;
      rH = *(const bf16x8*)(hpH + gb);
      rL = *(const bf16x8*)(hpL + gb);
    }
    const unsigned char* bcur = buf[ch & 1];
    f32x16 acc = {};
#pragma unroll
    for (int ks = 0; ks < 4; ++ks) {
      const int aoff = ((rowg * 8 + ks * 2 + lh) * 32 + l31) * 16;
      bf16x8 aL = *(const bf16x8*)(bcur + 8192 + aoff);
      bf16x8 aH = *(const bf16x8*)(bcur + aoff);
      acc = __builtin_amdgcn_mfma_f32_32x32x16_bf16(aL, bL[ks], acc, 0, 0, 0);
      acc = __builtin_amdgcn_mfma_f32_32x32x16_bf16(aL, bH[ks], acc, 0, 0, 0);
      acc = __builtin_amdgcn_mfma_f32_32x32x16_bf16(aH, bL[ks], acc, 0, 0, 0);
      acc = __builtin_amdgcn_mfma_f32_32x32x16_bf16(aH, bH[ks], acc, 0, 0, 0);
    }
    const int rowb = ch * 64 + rowg * 32 + 4 * lh;   // strip-local token base
#pragma unroll
    for (int rq = 0; rq < 4; ++rq) {   // tokens ascend within and across rq
      float4 pl = *(const float4*)&Pl[rowb + 8 * rq];
      const int tok0 = tstrip + rowb + 8 * rq;
      float kx = fmaf(-2.f, acc[4 * rq + 0], pl.x);
      if (kx < td4) tins5(td0, td1, td2, td3, td4, ti0, ti1, ti2, ti3, ti4, kx, tok0 + 0);
      float ky = fmaf(-2.f, acc[4 * rq + 1], pl.y);
      if (ky < td4) tins5(td0, td1, td2, td3, td4, ti0, ti1, ti2, ti3, ti4, ky, tok0 + 1);
      float kz = fmaf(-2.f, acc[4 * rq + 2], pl.z);
      if (kz < td4) tins5(td0, td1, td2, td3, td4, ti0, ti1, ti2, ti3, ti4, kz, tok0 + 2);
      float kw = fmaf(-2.f, acc[4 * rq + 3], pl.w);
      if (kw < td4) tins5(td0, td1, td2, td3, td4, ti0, ti1, ti2, ti3, ti4, kw, tok0 + 3);
    }
    if (ch < 15) {
      *(bf16x8*)(buf[(ch + 1) & 1] + tid * 16) = rH;
      *(bf16x8*)(buf[(ch + 1) & 1] + 8192 + tid * 16) = rL;
    }
    __syncthreads();
  }
  // merge lane <-> lane^32 (other lh rows, same code); snapshot first
  {
    float od0 = __shfl_xor(td0, 32, 64), od1 = __shfl_xor(td1, 32, 64),
          od2 = __shfl_xor(td2, 32, 64), od3 = __shfl_xor(td3, 32, 64),
          od4 = __shfl_xor(td4, 32, 64);
    int oi0 = __shfl_xor(ti0, 32, 64), oi1 = __shfl_xor(ti1, 32, 64),
        oi2 = __shfl_xor(ti2, 32, 64), oi3 = __shfl_xor(ti3, 32, 64),
        oi4 = __shfl_xor(ti4, 32, 64);
    lins5(td0, td1, td2, td3, td4, ti0, ti1, ti2, ti3, ti4, od0, oi0);
    lins5(td0, td1, td2, td3, td4, ti0, ti1, ti2, ti3, ti4, od1, oi1);
    lins5(td0, td1, td2, td3, td4, ti0, ti1, ti2, ti3, ti4, od2, oi2);
    lins5(td0, td1, td2, td3, td4, ti0, ti1, ti2, ti3, ti4, od3, oi3);
    lins5(td0, td1, td2, td3, td4, ti0, ti1, ti2, ti3, ti4, od4, oi4);
  }
  if (lane < 32) {
    sD[colg][rowg][l31][0] = td0; sD[colg][rowg][l31][1] = td1;
    sD[colg][rowg][l31][2] = td2; sD[colg][rowg][l31][3] = td3;
    sD[colg][rowg][l31][4] = td4;
    sI[colg][rowg][l31][0] = ti0; sI[colg][rowg][l31][1] = ti1;
    sI[colg][rowg][l31][2] = ti2; sI[colg][rowg][l31][3] = ti3;
    sI[colg][rowg][l31][4] = ti4;
  }
  __syncthreads();
  if (tid < 128) {
    const int cg = tid >> 5, cl = tid & 31;
    float rd0 = sD[cg][0][cl][0], rd1 = sD[cg][0][cl][1],
          rd2 = sD[cg][0][cl][2], rd3 = sD[cg][0][cl][3],
          rd4 = sD[cg][0][cl][4];
    int ri0 = sI[cg][0][cl][0], ri1 = sI[cg][0][cl][1],
        ri2 = sI[cg][0][cl][2], ri3 = sI[cg][0][cl][3],
        ri4 = sI[cg][0][cl][4];
#pragma unroll
    for (int s = 0; s < 5; ++s)
      lins5(rd0, rd1, rd2, rd3, rd4, ri0, ri1, ri2, ri3, ri4,
            sD[cg][1][cl][s], sI[cg][1][cl][s]);
    const int code = blockIdx.x * 128 + tid;
    const float e2c = e2g[code];    // kappa -> d (constant shift per code)
    size_t gb = (size_t)code * 40 + (size_t)blockIdx.y * 5;
    t5d[gb + 0] = rd0 + e2c; t5i[gb + 0] = ri0;
    t5d[gb + 1] = rd1 + e2c; t5i[gb + 1] = ri1;
    t5d[gb + 2] = rd2 + e2c; t5i[gb + 2] = ri2;
    t5d[gb + 3] = rd3 + e2c; t5i[gb + 3] = ri3;
    t5d[gb + 4] = rd4 + e2c; t5i[gb + 4] = ri4;
  }
}

// ---------------- Kernel 4: merge argmin, code, histogram, token loss ------
__global__ __launch_bounds__(256) void k_code(
    const float* __restrict__ amin_d, const int* __restrict__ amin_c,
    const float* __restrict__ hp, const float* __restrict__ E,
    const float* __restrict__ maskg,
    float* __restrict__ code_f, int* __restrict__ code_i,
    float* __restrict__ newcount, float* __restrict__ loss_tok) {
  const int wid = threadIdx.x >> 6;
  const int lane = threadIdx.x & 63;
  const int t = blockIdx.x * 4 + wid;
  float d = FLT_MAX;
  int c = 0x7fffffff;
  if (lane < 8) {
    d = amin_d[(size_t)t * 8 + lane];
    c = amin_c[(size_t)t * 8 + lane];
  }
#pragma unroll
  for (int o = 1; o <= 4; o <<= 1) {
    float od = __shfl_xor(d, o, 64);
    int oc = __shfl_xor(c, o, 64);
    if (od < d || (od == d && oc < c)) { d = od; c = oc; }
  }
  c = __shfl(c, 0, 64);
  if (maskg[t] == 0.f) c = 0;   // masked row: all dists 1e7 -> argmin = 0
  float a = hp[(size_t)t * 64 + lane];
  float e = E[(size_t)c * 64 + lane];
  float q = a + (e - a);
  float df = a - q;
  float ad = fabsf(df);
  float l = ad < 1.f ? 0.5f * df * df : ad - 0.5f;
#pragma unroll
  for (int o = 32; o > 0; o >>= 1) l += __shfl_xor(l, o, 64);
  if (lane == 0) {
    code_f[t] = (float)c;
    code_i[t] = c;
    loss_tok[t] = l;
    atomicAdd(&newcount[c], 1.0f);
  }
}

// ---------------- Kernel 5: q_out = E[code] @ proj_inv_w + b (MFMA) --------
__global__ __launch_bounds__(256, 2) void k_qout(
    const int* __restrict__ code_i,
    const unsigned short* __restrict__ EH, const unsigned short* __restrict__ EL,
    const unsigned short* __restrict__ wTH, const unsigned short* __restrict__ wTL,
    const float* __restrict__ bias, float* __restrict__ qout) {
  const int tid = threadIdx.x;
  const int w = tid >> 6, lane = tid & 63;
  const int l31 = lane & 31, lh = lane >> 5;
  const int rowg = w >> 1, colg = w & 1;
  const int tok_base = blockIdx.x * 64;
  const int col_base = blockIdx.y * 64;
  const int row_t = tok_base + rowg * 32 + l31;
  const int c = code_i[row_t];
  const int n = col_base + colg * 32 + l31;
  bf16x8 aH[4], aL[4], bH[4], bL[4];
#pragma unroll
  for (int ks = 0; ks < 4; ++ks) {
    aH[ks] = *(const bf16x8*)(EH + frag_off(c, ks, lh));
    aL[ks] = *(const bf16x8*)(EL + frag_off(c, ks, lh));
    bH[ks] = *(const bf16x8*)(wTH + frag_off(n, ks, lh));
    bL[ks] = *(const bf16x8*)(wTL + frag_off(n, ks, lh));
  }
  f32x16 c0 = {}, c1 = {}, c2 = {}, c3 = {};
#pragma unroll
  for (int ks = 0; ks < 4; ++ks) {
    c0 = __builtin_amdgcn_mfma_f32_32x32x16_bf16(aL[ks], bL[ks], c0, 0, 0, 0);
    c1 = __builtin_amdgcn_mfma_f32_32x32x16_bf16(aL[ks], bH[ks], c1, 0, 0, 0);
    c2 = __builtin_amdgcn_mfma_f32_32x32x16_bf16(aH[ks], bL[ks], c2, 0, 0, 0);
    c3 = __builtin_amdgcn_mfma_f32_32x32x16_bf16(aH[ks], bH[ks], c3, 0, 0, 0);
  }
  const float bc = bias[n];
#pragma unroll
  for (int r = 0; r < 16; ++r) {
    int row = rowg * 32 + (r & 3) + 8 * (r >> 2) + 4 * lh;
    float dot = ((c0[r] + c1[r]) + c2[r]) + c3[r];
    qout[(size_t)(tok_base + row) * 1024 + n] = dot + bc;
  }
}

// ---------------- Kernel 6: merge top5 + EMA update; block 2048 = vq_loss --
__global__ __launch_bounds__(256) void k_emb(
    const float* __restrict__ t5d, const int* __restrict__ t5i,
    const float* __restrict__ hp, const float* __restrict__ E,
    float* __restrict__ newemb,
    const float* __restrict__ loss_tok, const float* __restrict__ maskg,
    float* __restrict__ vq) {
  __shared__ float S[256], M[256];
  const int tid = threadIdx.x;
  if (blockIdx.x == 2048) {      // vq_loss reduction
    float s = 0.f, m = 0.f;
    const int base = tid * 32;
    for (int i = 0; i < 32; ++i) {
      float mm = maskg[base + i];
      s = fmaf(loss_tok[base + i], mm, s);
      m += mm;
    }
    S[tid] = s; M[tid] = m;
    __syncthreads();
    if (tid == 0) {
      float tot = 0.f;
      for (int b = 0; b < 4; ++b) {
        float sb = 0.f, mb = 0.f;
        for (int i = 0; i < 64; ++i) { sb += S[b * 64 + i]; mb += M[b * 64 + i]; }
        tot += sb / mb;
      }
      vq[0] = tot * 1.25f / 256.0f;
    }
    return;
  }
  const int wid = tid >> 6;
  const int lane = tid & 63;
  const int c = blockIdx.x * 4 + wid;
  float d = FLT_MAX;
  int idx = 0x7fffffff;
  if (lane < 40) {
    d = t5d[(size_t)c * 40 + lane];
    idx = t5i[(size_t)c * 40 + lane];
  }
  float seld[5]; int sel[5];
#pragma unroll
  for (int r = 0; r < 5; ++r) {
    float bd = d; int bi = idx;
#pragma unroll
    for (int o = 1; o <= 32; o <<= 1) {
      float od = __shfl_xor(bd, o, 64);
      int oi = __shfl_xor(bi, o, 64);
      if (od < bd || (od == bd && oi < bi)) { bd = od; bi = oi; }
    }
    seld[r] = bd; sel[r] = bi;
    if (idx == bi) d = FLT_MAX;   // token ids unique across strips
  }
  float m5 = fabsf(seld[0]);
#pragma unroll
  for (int r = 1; r < 5; ++r) m5 = fminf(m5, fabsf(seld[r]));
  float hf = 0.f;
#pragma unroll
  for (int r = 0; r < 5; ++r) hf += hp[(size_t)sel[r] * 64 + lane];
  hf = hf / 5.0f;
  float ev = E[(size_t)c * 64 + lane];
  float outv = (m5 > 0.1f) ? (ev * 0.995f + hf * (float)(1.0 - 0.995)) : ev;
  newemb[(size_t)c * 64 + lane] = outv;
}

// ---------------------------------------------------------------------------
extern "C" void kernel_launch(void* const* d_in, const int* in_sizes, int n_in,
                              void* d_out, int out_size, void* d_ws,
                              size_t ws_size, hipStream_t stream) {
  (void)in_sizes; (void)n_in; (void)out_size; (void)ws_size;
  const float* h          = (const float*)d_in[0];
  const float* mask       = (const float*)d_in[1];
  const float* proj_w     = (const float*)d_in[2];
  const float* proj_b     = (const float*)d_in[3];
  const float* proj_inv_w = (const float*)d_in[4];
  const float* proj_inv_b = (const float*)d_in[5];
  const float* emb        = (const float*)d_in[6];
  const float* count      = (const float*)d_in[7];

  float* out      = (float*)d_out;
  float* q_out    = out;                 // 8388608
  float* code_f   = out + 8388608;       // 8192
  float* vq       = out + 8396800;       // 1
  float* newemb   = out + 8396801;       // 524288
  float* newcount = out + 8921089;       // 8192

  float* ws = (float*)d_ws;
  float* hp_norm        = ws;                                  // 524288
  float* h2             = ws + 524288;                         // 8192
  float* E              = ws + 532480;                         // 524288
  float* e2             = ws + 1056768;                        // 8192
  unsigned short* hpH   = (unsigned short*)(ws + 1064960);     // 262144 f
  unsigned short* hpL   = (unsigned short*)(ws + 1327104);     // 262144 f
  unsigned short* EH    = (unsigned short*)(ws + 1589248);     // 262144 f
  unsigned short* EL    = (unsigned short*)(ws + 1851392);     // 262144 f
  unsigned short* wTH   = (unsigned short*)(ws + 2113536);     // 32768 f
  unsigned short* wTL   = (unsigned short*)(ws + 2146304);     // 32768 f
  float* amin_d         = ws + 2179072;                        // 65536 (8192*8)
  int*   amin_c         = (int*)(ws + 2244608);                // 65536
  int*   code_i         = (int*)(ws + 2310144);                // 8192
  float* t5d            = ws + 2318336;                        // 327680 (8192*40)
  int*   t5i            = (int*)(ws + 2646016);                // 327680
  float* loss_tok       = ws + 2973696;                        // 8192

  k_proj<<<512, 256, 0, stream>>>(h, proj_w, proj_b, hp_norm, h2, hpH, hpL);
  k_enorm<<<2096, 256, 0, stream>>>(emb, E, e2, EH, EL, count, newcount,
                                    proj_inv_w, wTH, wTL);
  k_argmin<<<dim3(64, 8), 512, 0, stream>>>(hpH, hpL, EH, EL, e2,
                                            amin_d, amin_c);
  k_top5<<<dim3(64, 8), 512, 0, stream>>>(hpH, hpL, EH, EL, h2, e2, mask,
                                          t5d, t5i);
  k_code<<<2048, 256, 0, stream>>>(amin_d, amin_c, hp_norm, E, mask,
                                   code_f, code_i, newcount, loss_tok);
  k_qout<<<dim3(128, 16), 256, 0, stream>>>(code_i, EH, EL, wTH, wTL,
                                            proj_inv_b, q_out);
  k_emb<<<2049, 256, 0, stream>>>(t5d, t5i, hp_norm, E, newemb,
                                  loss_tok, mask, vq);
}

// Round 11
// 155.430 us; speedup vs baseline: 1.7007x; 1.1115x over previous
//
#include <hip/hip_runtime.h>
#include <float.h>

// ---------------------------------------------------------------------------
// VQ layer forward, MI355X. B=4, L=2048 (8192 tokens), D=1024, VQ_DIM=64,
// K_CODES=8192, EMA_K=5.
// Round 11: k_top5 top-5 state -> packed u32 keys, branchless min/max ladder.
// key = (bits(kappa+4) & 0xFFFFFF00) | ((ch<<4)|r): positive-float bits order
// as unsigned; low 8 bits = unique ascending-token stream position => ties
// resolve numpy-stable automatically. 9 v_min/v_max per element, no branches,
// no exec-mask churn (round-10: ~20-op predicated chain ran for ALL elements,
// VALUBusy 86%). Decode once per strip; merges unchanged. Rest = round-10.
// ---------------------------------------------------------------------------

typedef __attribute__((ext_vector_type(8)))  short bf16x8;   // 8 bf16 = 4 VGPR
typedef __attribute__((ext_vector_type(16))) float f32x16;   // MFMA 32x32 acc

__device__ __forceinline__ unsigned short f2bf(float x) {
  unsigned u = __float_as_uint(x);
  unsigned r = (u + 0x7fffu + ((u >> 16) & 1u)) >> 16;   // RNE
  return (unsigned short)r;
}
__device__ __forceinline__ float bf2f(unsigned short b) {
  return __uint_as_float(((unsigned)b) << 16);
}
// fragment-major layout: entity-block(32) x ks(4) x lh(2) x lane(32) x 8 elems
__device__ __forceinline__ size_t frag_off(int e, int ks, int lh) {
  return ((size_t)((((e >> 5) * 4 + ks) * 2 + lh) * 32 + (e & 31))) * 8;
}

// branchless sorted-5-smallest insert on u32 keys (keys unique)
__device__ __forceinline__ void kins5(unsigned& s0, unsigned& s1, unsigned& s2,
                                      unsigned& s3, unsigned& s4, unsigned k) {
  unsigned t = k, m;
  m = min(s0, t); t = max(s0, t); s0 = m;
  m = min(s1, t); t = max(s1, t); s1 = m;
  m = min(s2, t); t = max(s2, t); s2 = m;
  m = min(s3, t); t = max(s3, t); s3 = m;
  s4 = min(s4, t);
}
// sorted-5 insert, lexicographic (d, idx) — order-independent merges
__device__ __forceinline__ void lins5(float& d0, float& d1, float& d2,
                                      float& d3, float& d4, int& i0, int& i1,
                                      int& i2, int& i3, int& i4, float dv,
                                      int iv) {
  if (dv < d4 || (dv == d4 && iv < i4)) {
    d4 = dv; i4 = iv;
    if (d4 < d3 || (d4 == d3 && i4 < i3)) { float t = d3; d3 = d4; d4 = t; int u = i3; i3 = i4; i4 = u; }
    if (d3 < d2 || (d3 == d2 && i3 < i2)) { float t = d2; d2 = d3; d3 = t; int u = i2; i2 = i3; i3 = u; }
    if (d2 < d1 || (d2 == d1 && i2 < i1)) { float t = d1; d1 = d2; d2 = t; int u = i1; i1 = i2; i2 = u; }
    if (d1 < d0 || (d1 == d0 && i1 < i0)) { float t = d0; d0 = d1; d1 = t; int u = i0; i0 = i1; i1 = u; }
  }
}

// ---------------- Kernel 1: hp = normalize(h @ proj_w + b), + bf16 split ---
__global__ __launch_bounds__(256) void k_proj(
    const float* __restrict__ h, const float* __restrict__ w,
    const float* __restrict__ bias, float* __restrict__ hp_norm,
    float* __restrict__ h2, unsigned short* __restrict__ hpH,
    unsigned short* __restrict__ hpL) {
  __shared__ __align__(16) float hs[16 * 68];   // 16 tok x 64 k (pad 68)
  __shared__ __align__(16) float ws[64 * 64];   // 64 k x 64 dim
  const int tid = threadIdx.x;
  const int tb = blockIdx.x * 16;
  const int tok = tid >> 4;
  const int dimg = tid & 15;
  const float4* h4 = (const float4*)h;
  const float4* w4 = (const float4*)w;
  float4* ws4 = (float4*)ws;
  float4 acc = {0.f, 0.f, 0.f, 0.f};
  for (int ch = 0; ch < 16; ++ch) {
    __syncthreads();
    *(float4*)&hs[tok * 68 + dimg * 4] = h4[(size_t)(tb + tok) * 256 + ch * 16 + dimg];
#pragma unroll
    for (int i = 0; i < 4; ++i) {
      int idx = tid + i * 256;
      int k = idx >> 4, dq = idx & 15;
      ws4[k * 16 + dq] = w4[(size_t)(ch * 64 + k) * 16 + dq];
    }
    __syncthreads();
#pragma unroll 8
    for (int k = 0; k < 64; ++k) {
      float hv = hs[tok * 68 + k];
      float4 wv = *(const float4*)&ws[k * 64 + dimg * 4];
      acc.x = fmaf(hv, wv.x, acc.x);
      acc.y = fmaf(hv, wv.y, acc.y);
      acc.z = fmaf(hv, wv.z, acc.z);
      acc.w = fmaf(hv, wv.w, acc.w);
    }
  }
  const float4 bv = ((const float4*)bias)[dimg];
  acc.x += bv.x; acc.y += bv.y; acc.z += bv.z; acc.w += bv.w;
  float sq = acc.x * acc.x + acc.y * acc.y + acc.z * acc.z + acc.w * acc.w;
#pragma unroll
  for (int o = 1; o <= 8; o <<= 1) sq += __shfl_xor(sq, o, 64);
  float nrm = sqrtf(sq);
  float4 vn;
  vn.x = acc.x / nrm; vn.y = acc.y / nrm; vn.z = acc.z / nrm; vn.w = acc.w / nrm;
  ((float4*)hp_norm)[(size_t)(tb + tok) * 16 + dimg] = vn;
  unsigned short hx = f2bf(vn.x), hy = f2bf(vn.y), hz = f2bf(vn.z), hw = f2bf(vn.w);
  uint2 hi_pack, lo_pack;
  hi_pack.x = (unsigned)hx | ((unsigned)hy << 16);
  hi_pack.y = (unsigned)hz | ((unsigned)hw << 16);
  lo_pack.x = (unsigned)f2bf(vn.x - bf2f(hx)) | ((unsigned)f2bf(vn.y - bf2f(hy)) << 16);
  lo_pack.y = (unsigned)f2bf(vn.z - bf2f(hz)) | ((unsigned)f2bf(vn.w - bf2f(hw)) << 16);
  {
    int ks = dimg >> 2, lh = (dimg >> 1) & 1, half = dimg & 1;
    size_t off = frag_off(tb + tok, ks, lh) + half * 4;
    *(uint2*)(hpH + off) = hi_pack;
    *(uint2*)(hpL + off) = lo_pack;
  }
  float s2 = vn.x * vn.x + vn.y * vn.y + vn.z * vn.z + vn.w * vn.w;
#pragma unroll
  for (int o = 1; o <= 8; o <<= 1) s2 += __shfl_xor(s2, o, 64);
  if (dimg == 0) h2[tb + tok] = s2;
}

// ---------------- Kernel 2: E-normalize + initcount + wT transpose ---------
// grid 2096: [0,2048) enorm, [2048,2080) newcount=count, [2080,2096) wT.
__global__ __launch_bounds__(256) void k_enorm(
    const float* __restrict__ emb, float* __restrict__ E,
    float* __restrict__ e2, unsigned short* __restrict__ EH,
    unsigned short* __restrict__ EL,
    const float* __restrict__ cnt, float* __restrict__ ncnt,
    const float* __restrict__ wiv, unsigned short* __restrict__ wTH,
    unsigned short* __restrict__ wTL) {
  __shared__ float tile[64][65];
  const int b = blockIdx.x;
  const int tid = threadIdx.x;
  if (b >= 2080) {               // transpose proj_inv_w [64][1024] -> [n][k]
    const int n0 = (b - 2080) * 64;
    const float4* w4 = (const float4*)wiv;
#pragma unroll
    for (int i = 0; i < 4; ++i) {
      int idx = tid + i * 256;
      int k = idx >> 4, nq = idx & 15;
      float4 v = w4[k * 256 + (n0 >> 2) + nq];
      tile[nq * 4 + 0][k] = v.x;
      tile[nq * 4 + 1][k] = v.y;
      tile[nq * 4 + 2][k] = v.z;
      tile[nq * 4 + 3][k] = v.w;
    }
    __syncthreads();
    const int n = tid >> 2;
    const int k0 = (tid & 3) * 16;
#pragma unroll
    for (int j = 0; j < 16; j += 4) {
      int k = k0 + j;
      float x0 = tile[n][k], x1 = tile[n][k + 1], x2 = tile[n][k + 2],
            x3 = tile[n][k + 3];
      unsigned short h0 = f2bf(x0), h1 = f2bf(x1), h2_ = f2bf(x2), h3 = f2bf(x3);
      uint2 hp_, lp_;
      hp_.x = (unsigned)h0 | ((unsigned)h1 << 16);
      hp_.y = (unsigned)h2_ | ((unsigned)h3 << 16);
      lp_.x = (unsigned)f2bf(x0 - bf2f(h0)) | ((unsigned)f2bf(x1 - bf2f(h1)) << 16);
      lp_.y = (unsigned)f2bf(x2 - bf2f(h2_)) | ((unsigned)f2bf(x3 - bf2f(h3)) << 16);
      size_t off = frag_off(n0 + n, k >> 4, (k >> 3) & 1) + (k & 7);
      *(uint2*)(wTH + off) = hp_;
      *(uint2*)(wTL + off) = lp_;
    }
    return;
  }
  if (b >= 2048) {               // new_count = count
    int i = (b - 2048) * 256 + tid;
    ncnt[i] = cnt[i];
    return;
  }
  const int c = b * 4 + (tid >> 6);
  const int lane = tid & 63;
  float v = emb[(size_t)c * 64 + lane];
  float sq = v * v;
#pragma unroll
  for (int o = 32; o > 0; o >>= 1) sq += __shfl_xor(sq, o, 64);
  float vn = v / sqrtf(sq);
  E[(size_t)c * 64 + lane] = vn;
  unsigned short hb = f2bf(vn);
  size_t off = frag_off(c, lane >> 4, (lane >> 3) & 1) + (lane & 7);
  EH[off] = hb;
  EL[off] = f2bf(vn - bf2f(hb));
  float s2 = vn * vn;
#pragma unroll
  for (int o = 32; o > 0; o >>= 1) s2 += __shfl_xor(s2, o, 64);
  if (lane == 0) e2[c] = s2;
}

// ---------------- Kernel 3a: argmin over codes (u-basis, LDS-streamed) -----
// grid (64 token-tiles, 8 code-strips), 512 thr = 8 waves (4 rowg x 2 colg).
__global__ __launch_bounds__(512, 4) void k_argmin(
    const unsigned short* __restrict__ hpH, const unsigned short* __restrict__ hpL,
    const unsigned short* __restrict__ EHg, const unsigned short* __restrict__ ELg,
    const float* __restrict__ e2g,
    float* __restrict__ amin_d, int* __restrict__ amin_c) {
  __shared__ __align__(16) unsigned char buf[2][16384];  // H [0,8K), L [8K,16K)
  __shared__ float e2l[1024];
  __shared__ float mD[2][128];
  __shared__ int   mC[2][128];
  const int tid = threadIdx.x;
  const int w = tid >> 6, lane = tid & 63;
  const int l31 = lane & 31, lh = lane >> 5;
  const int rowg = w >> 1, colg = w & 1;
  const int tok_base = blockIdx.x * 128;
  const int cstrip = blockIdx.y * 1024;
  const int row_t = tok_base + rowg * 32 + l31;
  bf16x8 aH[4], aL[4];
#pragma unroll
  for (int ks = 0; ks < 4; ++ks) {
    aH[ks] = *(const bf16x8*)(hpH + frag_off(row_t, ks, lh));
    aL[ks] = *(const bf16x8*)(hpL + frag_off(row_t, ks, lh));
  }
  e2l[tid] = e2g[cstrip + tid];
  e2l[tid + 512] = e2g[cstrip + tid + 512];
  float bu[16]; int bc[16];
#pragma unroll
  for (int r = 0; r < 16; ++r) { bu[r] = FLT_MAX; bc[r] = 0x7fffffff; }
  bf16x8 rH, rL;
  {
    size_t gb = (size_t)(blockIdx.y * 32) * 2048 + (size_t)tid * 8;
    rH = *(const bf16x8*)(EHg + gb);
    rL = *(const bf16x8*)(ELg + gb);
    *(bf16x8*)(buf[0] + tid * 16) = rH;
    *(bf16x8*)(buf[0] + 8192 + tid * 16) = rL;
  }
  __syncthreads();
  for (int ch = 0; ch < 16; ++ch) {
    if (ch < 15) {   // early-issue next chunk's loads; MFMA hides latency
      size_t gb = (size_t)(blockIdx.y * 32 + (ch + 1) * 2) * 2048 + (size_t)tid * 8;
      rH = *(const bf16x8*)(EHg + gb);
      rL = *(const bf16x8*)(ELg + gb);
    }
    const unsigned char* bcur = buf[ch & 1];
    f32x16 acc = {};
#pragma unroll
    for (int ks = 0; ks < 4; ++ks) {
      const int boff = ((colg * 8 + ks * 2 + lh) * 32 + l31) * 16;
      bf16x8 bL = *(const bf16x8*)(bcur + 8192 + boff);
      bf16x8 bH = *(const bf16x8*)(bcur + boff);
      acc = __builtin_amdgcn_mfma_f32_32x32x16_bf16(aL[ks], bL, acc, 0, 0, 0);
      acc = __builtin_amdgcn_mfma_f32_32x32x16_bf16(aL[ks], bH, acc, 0, 0, 0);
      acc = __builtin_amdgcn_mfma_f32_32x32x16_bf16(aH[ks], bL, acc, 0, 0, 0);
      acc = __builtin_amdgcn_mfma_f32_32x32x16_bf16(aH[ks], bH, acc, 0, 0, 0);
    }
    const int mycode = cstrip + ch * 64 + colg * 32 + l31;
    const float e2c = e2l[ch * 64 + colg * 32 + l31];
#pragma unroll
    for (int r = 0; r < 16; ++r) {
      // u = e2c - 2*dot; differs from d by +h2[token] (row-constant) ->
      // same argmin. Codes ascend across chunks: strict < keeps lowest.
      float u = fmaf(-2.f, acc[r], e2c);
      if (u < bu[r]) { bu[r] = u; bc[r] = mycode; }
    }
    if (ch < 15) {
      *(bf16x8*)(buf[(ch + 1) & 1] + tid * 16) = rH;
      *(bf16x8*)(buf[(ch + 1) & 1] + 8192 + tid * 16) = rL;
    }
    __syncthreads();
  }
#pragma unroll
  for (int r = 0; r < 16; ++r) {
#pragma unroll
    for (int o = 1; o <= 16; o <<= 1) {
      float ou = __shfl_xor(bu[r], o, 64);
      int oc = __shfl_xor(bc[r], o, 64);
      if (ou < bu[r] || (ou == bu[r] && oc < bc[r])) { bu[r] = ou; bc[r] = oc; }
    }
  }
  if (l31 == 0) {
#pragma unroll
    for (int r = 0; r < 16; ++r) {
      const int roff = rowg * 32 + (r & 3) + 8 * (r >> 2) + 4 * lh;
      mD[colg][roff] = bu[r];
      mC[colg][roff] = bc[r];
    }
  }
  __syncthreads();
  if (tid < 128) {
    float d0 = mD[0][tid], d1 = mD[1][tid];
    int c0 = mC[0][tid], c1 = mC[1][tid];
    if (d1 < d0 || (d1 == d0 && c1 < c0)) { d0 = d1; c0 = c1; }
    const int t = tok_base + tid;
    amin_d[(size_t)t * 8 + blockIdx.y] = d0;
    amin_c[(size_t)t * 8 + blockIdx.y] = c0;
  }
}

// ---------------- Kernel 3b: top-5 tokens per code (packed u32 keys) -------
// grid (64 code-tiles, 8 token-strips), 512 thr = 8 waves (2 rowg x 4 colg).
// 128 codes resident in B-frags; 1024 tokens stream in 16 chunks of 64.
// key = (bits(kappa+4) & 0xFFFFFF00) | (ch<<4|r): unsigned order == (d,tok)
// lexicographic (enc ascending == token ascending per lane). Branchless
// 9-op min/max ladder per element. kappa = Pl[t] - 2*dot, Pl biased +4 so
// kappa+4 > 0 (bits order as unsigned). d = trunc(kappa+4) - 4 + e2c at end.
__global__ __launch_bounds__(512, 4) void k_top5(
    const unsigned short* __restrict__ hpH, const unsigned short* __restrict__ hpL,
    const unsigned short* __restrict__ EHg, const unsigned short* __restrict__ ELg,
    const float* __restrict__ h2g, const float* __restrict__ e2g,
    const float* __restrict__ maskg,
    float* __restrict__ t5d, int* __restrict__ t5i) {
  __shared__ __align__(16) unsigned char buf[2][16384];  // H [0,8K), L [8K,16K)
  __shared__ __align__(16) float Pl[1024];   // m*h2 + 1e7*(1-m) + 4
  __shared__ float sD[4][2][32][5];
  __shared__ int   sI[4][2][32][5];
  const int tid = threadIdx.x;
  const int w = tid >> 6, lane = tid & 63;
  const int l31 = lane & 31, lh = lane >> 5;
  const int rowg = w >> 2, colg = w & 3;
  const int code_t = blockIdx.x * 128 + colg * 32 + l31;   // resident code
  const int tstrip = blockIdx.y * 1024;
  bf16x8 bH[4], bL[4];
#pragma unroll
  for (int ks = 0; ks < 4; ++ks) {
    bH[ks] = *(const bf16x8*)(EHg + frag_off(code_t, ks, lh));
    bL[ks] = *(const bf16x8*)(ELg + frag_off(code_t, ks, lh));
  }
  {
    int t0 = tid, t1 = tid + 512;
    float m0 = maskg[tstrip + t0], m1 = maskg[tstrip + t1];
    Pl[t0] = fmaf(h2g[tstrip + t0], m0, 1.0e7f * (1.f - m0) + 4.0f);
    Pl[t1] = fmaf(h2g[tstrip + t1], m1, 1.0e7f * (1.f - m1) + 4.0f);
  }
  unsigned s0 = 0xFFFFFFFFu, s1 = 0xFFFFFFFFu, s2 = 0xFFFFFFFFu,
           s3 = 0xFFFFFFFFu, s4 = 0xFFFFFFFFu;
  bf16x8 rH, rL;
  {
    size_t gb = (size_t)(blockIdx.y * 32) * 2048 + (size_t)tid * 8;
    rH = *(const bf16x8*)(hpH + gb);
    rL = *(const bf16x8*)(hpL + gb);
    *(bf16x8*)(buf[0] + tid * 16) = rH;
    *(bf16x8*)(buf[0] + 8192 + tid * 16) = rL;
  }
  __syncthreads();
  for (int ch = 0; ch < 16; ++ch) {
    if (ch < 15) {
      size_t gb = (size_t)(blockIdx.y * 32 + (ch + 1) * 2) * 2048 + (size_t)tid * 8;
      rH = *(const bf16x8*)(hpH + gb);
      rL = *(const bf16x8*)(hpL + gb);
    }
    const unsigned char* bcur = buf[ch & 1];
    f32x16 acc = {};
#pragma unroll
    for (int ks = 0; ks < 4; ++ks) {
      const int aoff = ((rowg * 8 + ks * 2 + lh) * 32 + l31) * 16;
      bf16x8 aL = *(const bf16x8*)(bcur + 8192 + aoff);
      bf16x8 aH = *(const bf16x8*)(bcur + aoff);
      acc = __builtin_amdgcn_mfma_f32_32x32x16_bf16(aL, bL[ks], acc, 0, 0, 0);
      acc = __builtin_amdgcn_mfma_f32_32x32x16_bf16(aL, bH[ks], acc, 0, 0, 0);
      acc = __builtin_amdgcn_mfma_f32_32x32x16_bf16(aH, bL[ks], acc, 0, 0, 0);
      acc = __builtin_amdgcn_mfma_f32_32x32x16_bf16(aH, bH[ks], acc, 0, 0, 0);
    }
    const int rowb = ch * 64 + rowg * 32 + 4 * lh;   // strip-local token base
    const unsigned encb = (unsigned)(ch << 4);
#pragma unroll
    for (int rq = 0; rq < 4; ++rq) {   // tokens ascend within and across rq
      float4 pl = *(const float4*)&Pl[rowb + 8 * rq];
      float kx = fmaf(-2.f, acc[4 * rq + 0], pl.x);
      kins5(s0, s1, s2, s3, s4,
            (__float_as_uint(kx) & 0xFFFFFF00u) | (encb + 4 * rq + 0));
      float ky = fmaf(-2.f, acc[4 * rq + 1], pl.y);
      kins5(s0, s1, s2, s3, s4,
            (__float_as_uint(ky) & 0xFFFFFF00u) | (encb + 4 * rq + 1));
      float kz = fmaf(-2.f, acc[4 * rq + 2], pl.z);
      kins5(s0, s1, s2, s3, s4,
            (__float_as_uint(kz) & 0xFFFFFF00u) | (encb + 4 * rq + 2));
      float kw = fmaf(-2.f, acc[4 * rq + 3], pl.w);
      kins5(s0, s1, s2, s3, s4,
            (__float_as_uint(kw) & 0xFFFFFF00u) | (encb + 4 * rq + 3));
    }
    if (ch < 15) {
      *(bf16x8*)(buf[(ch + 1) & 1] + tid * 16) = rH;
      *(bf16x8*)(buf[(ch + 1) & 1] + 8192 + tid * 16) = rL;
    }
    __syncthreads();
  }
  // decode my 5 sorted keys -> (kappa'-trunc, global token). Keys sorted
  // ascending == (d, token) lexicographic; strips have 1024 >= 5 candidates
  // so no sentinel survives.
  float td0, td1, td2, td3, td4;
  int ti0, ti1, ti2, ti3, ti4;
  {
    auto dec = [&](unsigned k, float& d, int& i) {
      d = __uint_as_float(k & 0xFFFFFF00u);
      int enc = (int)(k & 255u);
      int r = enc & 15, chh = enc >> 4;
      i = tstrip + chh * 64 + rowg * 32 + lh * 4 + (r & 3) + 8 * (r >> 2);
    };
    dec(s0, td0, ti0); dec(s1, td1, ti1); dec(s2, td2, ti2);
    dec(s3, td3, ti3); dec(s4, td4, ti4);
  }
  // merge lane <-> lane^32 (other lh rows, same code); snapshot first
  {
    float od0 = __shfl_xor(td0, 32, 64), od1 = __shfl_xor(td1, 32, 64),
          od2 = __shfl_xor(td2, 32, 64), od3 = __shfl_xor(td3, 32, 64),
          od4 = __shfl_xor(td4, 32, 64);
    int oi0 = __shfl_xor(ti0, 32, 64), oi1 = __shfl_xor(ti1, 32, 64),
        oi2 = __shfl_xor(ti2, 32, 64), oi3 = __shfl_xor(ti3, 32, 64),
        oi4 = __shfl_xor(ti4, 32, 64);
    lins5(td0, td1, td2, td3, td4, ti0, ti1, ti2, ti3, ti4, od0, oi0);
    lins5(td0, td1, td2, td3, td4, ti0, ti1, ti2, ti3, ti4, od1, oi1);
    lins5(td0, td1, td2, td3, td4, ti0, ti1, ti2, ti3, ti4, od2, oi2);
    lins5(td0, td1, td2, td3, td4, ti0, ti1, ti2, ti3, ti4, od3, oi3);
    lins5(td0, td1, td2, td3, td4, ti0, ti1, ti2, ti3, ti4, od4, oi4);
  }
  if (lane < 32) {
    sD[colg][rowg][l31][0] = td0; sD[colg][rowg][l31][1] = td1;
    sD[colg][rowg][l31][2] = td2; sD[colg][rowg][l31][3] = td3;
    sD[colg][rowg][l31][4] = td4;
    sI[colg][rowg][l31][0] = ti0; sI[colg][rowg][l31][1] = ti1;
    sI[colg][rowg][l31][2] = ti2; sI[colg][rowg][l31][3] = ti3;
    sI[colg][rowg][l31][4] = ti4;
  }
  __syncthreads();
  if (tid < 128) {
    const int cg = tid >> 5, cl = tid & 31;
    float rd0 = sD[cg][0][cl][0], rd1 = sD[cg][0][cl][1],
          rd2 = sD[cg][0][cl][2], rd3 = sD[cg][0][cl][3],
          rd4 = sD[cg][0][cl][4];
    int ri0 = sI[cg][0][cl][0], ri1 = sI[cg][0][cl][1],
        ri2 = sI[cg][0][cl][2], ri3 = sI[cg][0][cl][3],
        ri4 = sI[cg][0][cl][4];
#pragma unroll
    for (int s = 0; s < 5; ++s)
      lins5(rd0, rd1, rd2, rd3, rd4, ri0, ri1, ri2, ri3, ri4,
            sD[cg][1][cl][s], sI[cg][1][cl][s]);
    const int code = blockIdx.x * 128 + tid;
    const float sh = e2g[code] - 4.0f;   // kappa'+e2c-4 = d (truncated)
    size_t gb = (size_t)code * 40 + (size_t)blockIdx.y * 5;
    t5d[gb + 0] = rd0 + sh; t5i[gb + 0] = ri0;
    t5d[gb + 1] = rd1 + sh; t5i[gb + 1] = ri1;
    t5d[gb + 2] = rd2 + sh; t5i[gb + 2] = ri2;
    t5d[gb + 3] = rd3 + sh; t5i[gb + 3] = ri3;
    t5d[gb + 4] = rd4 + sh; t5i[gb + 4] = ri4;
  }
}

// ---------------- Kernel 4: merge argmin, code, histogram, token loss ------
__global__ __launch_bounds__(256) void k_code(
    const float* __restrict__ amin_d, const int* __restrict__ amin_c,
    const float* __restrict__ hp, const float* __restrict__ E,
    const float* __restrict__ maskg,
    float* __restrict__ code_f, int* __restrict__ code_i,
    float* __restrict__ newcount, float* __restrict__ loss_tok) {
  const int wid = threadIdx.x >> 6;
  const int lane = threadIdx.x & 63;
  const int t = blockIdx.x * 4 + wid;
  float d = FLT_MAX;
  int c = 0x7fffffff;
  if (lane < 8) {
    d = amin_d[(size_t)t * 8 + lane];
    c = amin_c[(size_t)t * 8 + lane];
  }
#pragma unroll
  for (int o = 1; o <= 4; o <<= 1) {
    float od = __shfl_xor(d, o, 64);
    int oc = __shfl_xor(c, o, 64);
    if (od < d || (od == d && oc < c)) { d = od; c = oc; }
  }
  c = __shfl(c, 0, 64);
  if (maskg[t] == 0.f) c = 0;   // masked row: all dists 1e7 -> argmin = 0
  float a = hp[(size_t)t * 64 + lane];
  float e = E[(size_t)c * 64 + lane];
  float q = a + (e - a);
  float df = a - q;
  float ad = fabsf(df);
  float l = ad < 1.f ? 0.5f * df * df : ad - 0.5f;
#pragma unroll
  for (int o = 32; o > 0; o >>= 1) l += __shfl_xor(l, o, 64);
  if (lane == 0) {
    code_f[t] = (float)c;
    code_i[t] = c;
    loss_tok[t] = l;
    atomicAdd(&newcount[c], 1.0f);
  }
}

// ---------------- Kernel 5: q_out = E[code] @ proj_inv_w + b (MFMA) --------
__global__ __launch_bounds__(256, 2) void k_qout(
    const int* __restrict__ code_i,
    const unsigned short* __restrict__ EH, const unsigned short* __restrict__ EL,
    const unsigned short* __restrict__ wTH, const unsigned short* __restrict__ wTL,
    const float* __restrict__ bias, float* __restrict__ qout) {
  const int tid = threadIdx.x;
  const int w = tid >> 6, lane = tid & 63;
  const int l31 = lane & 31, lh = lane >> 5;
  const int rowg = w >> 1, colg = w & 1;
  const int tok_base = blockIdx.x * 64;
  const int col_base = blockIdx.y * 64;
  const int row_t = tok_base + rowg * 32 + l31;
  const int c = code_i[row_t];
  const int n = col_base + colg * 32 + l31;
  bf16x8 aH[4], aL[4], bH[4], bL[4];
#pragma unroll
  for (int ks = 0; ks < 4; ++ks) {
    aH[ks] = *(const bf16x8*)(EH + frag_off(c, ks, lh));
    aL[ks] = *(const bf16x8*)(EL + frag_off(c, ks, lh));
    bH[ks] = *(const bf16x8*)(wTH + frag_off(n, ks, lh));
    bL[ks] = *(const bf16x8*)(wTL + frag_off(n, ks, lh));
  }
  f32x16 c0 = {}, c1 = {}, c2 = {}, c3 = {};
#pragma unroll
  for (int ks = 0; ks < 4; ++ks) {
    c0 = __builtin_amdgcn_mfma_f32_32x32x16_bf16(aL[ks], bL[ks], c0, 0, 0, 0);
    c1 = __builtin_amdgcn_mfma_f32_32x32x16_bf16(aL[ks], bH[ks], c1, 0, 0, 0);
    c2 = __builtin_amdgcn_mfma_f32_32x32x16_bf16(aH[ks], bL[ks], c2, 0, 0, 0);
    c3 = __builtin_amdgcn_mfma_f32_32x32x16_bf16(aH[ks], bH[ks], c3, 0, 0, 0);
  }
  const float bc = bias[n];
#pragma unroll
  for (int r = 0; r < 16; ++r) {
    int row = rowg * 32 + (r & 3) + 8 * (r >> 2) + 4 * lh;
    float dot = ((c0[r] + c1[r]) + c2[r]) + c3[r];
    qout[(size_t)(tok_base + row) * 1024 + n] = dot + bc;
  }
}

// ---------------- Kernel 6: merge top5 + EMA update; block 2048 = vq_loss --
__global__ __launch_bounds__(256) void k_emb(
    const float* __restrict__ t5d, const int* __restrict__ t5i,
    const float* __restrict__ hp, const float* __restrict__ E,
    float* __restrict__ newemb,
    const float* __restrict__ loss_tok, const float* __restrict__ maskg,
    float* __restrict__ vq) {
  __shared__ float S[256], M[256];
  const int tid = threadIdx.x;
  if (blockIdx.x == 2048) {      // vq_loss reduction
    float s = 0.f, m = 0.f;
    const int base = tid * 32;
    for (int i = 0; i < 32; ++i) {
      float mm = maskg[base + i];
      s = fmaf(loss_tok[base + i], mm, s);
      m += mm;
    }
    S[tid] = s; M[tid] = m;
    __syncthreads();
    if (tid == 0) {
      float tot = 0.f;
      for (int b = 0; b < 4; ++b) {
        float sb = 0.f, mb = 0.f;
        for (int i = 0; i < 64; ++i) { sb += S[b * 64 + i]; mb += M[b * 64 + i]; }
        tot += sb / mb;
      }
      vq[0] = tot * 1.25f / 256.0f;
    }
    return;
  }
  const int wid = tid >> 6;
  const int lane = tid & 63;
  const int c = blockIdx.x * 4 + wid;
  float d = FLT_MAX;
  int idx = 0x7fffffff;
  if (lane < 40) {
    d = t5d[(size_t)c * 40 + lane];
    idx = t5i[(size_t)c * 40 + lane];
  }
  float seld[5]; int sel[5];
#pragma unroll
  for (int r = 0; r < 5; ++r) {
    float bd = d; int bi = idx;
#pragma unroll
    for (int o = 1; o <= 32; o <<= 1) {
      float od = __shfl_xor(bd, o, 64);
      int oi = __shfl_xor(bi, o, 64);
      if (od < bd || (od == bd && oi < bi)) { bd = od; bi = oi; }
    }
    seld[r] = bd; sel[r] = bi;
    if (idx == bi) d = FLT_MAX;   // token ids unique across strips
  }
  float m5 = fabsf(seld[0]);
#pragma unroll
  for (int r = 1; r < 5; ++r) m5 = fminf(m5, fabsf(seld[r]));
  float hf = 0.f;
#pragma unroll
  for (int r = 0; r < 5; ++r) hf += hp[(size_t)sel[r] * 64 + lane];
  hf = hf / 5.0f;
  float ev = E[(size_t)c * 64 + lane];
  float outv = (m5 > 0.1f) ? (ev * 0.995f + hf * (float)(1.0 - 0.995)) : ev;
  newemb[(size_t)c * 64 + lane] = outv;
}

// ---------------------------------------------------------------------------
extern "C" void kernel_launch(void* const* d_in, const int* in_sizes, int n_in,
                              void* d_out, int out_size, void* d_ws,
                              size_t ws_size, hipStream_t stream) {
  (void)in_sizes; (void)n_in; (void)out_size; (void)ws_size;
  const float* h          = (const float*)d_in[0];
  const float* mask       = (const float*)d_in[1];
  const float* proj_w     = (const float*)d_in[2];
  const float* proj_b     = (const float*)d_in[3];
  const float* proj_inv_w = (const float*)d_in[4];
  const float* proj_inv_b = (const float*)d_in[5];
  const float* emb        = (const float*)d_in[6];
  const float* count      = (const float*)d_in[7];

  float* out      = (float*)d_out;
  float* q_out    = out;                 // 8388608
  float* code_f   = out + 8388608;       // 8192
  float* vq       = out + 8396800;       // 1
  float* newemb   = out + 8396801;       // 524288
  float* newcount = out + 8921089;       // 8192

  float* ws = (float*)d_ws;
  float* hp_norm        = ws;                                  // 524288
  float* h2             = ws + 524288;                         // 8192
  float* E              = ws + 532480;                         // 524288
  float* e2             = ws + 1056768;                        // 8192
  unsigned short* hpH   = (unsigned short*)(ws + 1064960);     // 262144 f
  unsigned short* hpL   = (unsigned short*)(ws + 1327104);     // 262144 f
  unsigned short* EH    = (unsigned short*)(ws + 1589248);     // 262144 f
  unsigned short* EL    = (unsigned short*)(ws + 1851392);     // 262144 f
  unsigned short* wTH   = (unsigned short*)(ws + 2113536);     // 32768 f
  unsigned short* wTL   = (unsigned short*)(ws + 2146304);     // 32768 f
  float* amin_d         = ws + 2179072;                        // 65536 (8192*8)
  int*   amin_c         = (int*)(ws + 2244608);                // 65536
  int*   code_i         = (int*)(ws + 2310144);                // 8192
  float* t5d            = ws + 2318336;                        // 327680 (8192*40)
  int*   t5i            = (int*)(ws + 2646016);                // 327680
  float* loss_tok       = ws + 2973696;                        // 8192

  k_proj<<<512, 256, 0, stream>>>(h, proj_w, proj_b, hp_norm, h2, hpH, hpL);
  k_enorm<<<2096, 256, 0, stream>>>(emb, E, e2, EH, EL, count, newcount,
                                    proj_inv_w, wTH, wTL);
  k_argmin<<<dim3(64, 8), 512, 0, stream>>>(hpH, hpL, EH, EL, e2,
                                            amin_d, amin_c);
  k_top5<<<dim3(64, 8), 512, 0, stream>>>(hpH, hpL, EH, EL, h2, e2, mask,
                                          t5d, t5i);
  k_code<<<2048, 256, 0, stream>>>(amin_d, amin_c, hp_norm, E, mask,
                                   code_f, code_i, newcount, loss_tok);
  k_qout<<<dim3(128, 16), 256, 0, stream>>>(code_i, EH, EL, wTH, wTL,
                                            proj_inv_b, q_out);
  k_emb<<<2049, 256, 0, stream>>>(t5d, t5i, hp_norm, E, newemb,
                                  loss_tok, mask, vq);
}